// Round 1
// baseline (408.194 us; speedup 1.0000x reference)
//
#include <hip/hip_runtime.h>
#include <hip/hip_cooperative_groups.h>
#include <math.h>

typedef __attribute__((ext_vector_type(8))) short short8;
typedef __attribute__((ext_vector_type(4))) float f32x4;

// ---- workspace layout (float offsets) ---- total 905216 floats = 3.62 MB
#define WS_SPART 0          // srr partials [32][8192]           -> 262144
#define WS_GPART 262144     // g partials [512][64]              -> 294912
#define WS_WPART 294912     // wsum partials [512][2]            -> 295936
#define WS_CPART 295936     // colsum partials [5][125*64]       -> 335936
#define WS_T1R   335936
#define WS_T1C   336000
#define WS_AL    336064
#define WS_BE    336128
#define WS_GA    336192
#define WS_DE    336256
#define WS_ECP   336320
#define WS_ECN   336384
#define WS_W     336448     // w for sweep 0 only
#define WS_MUZ   336512
#define WS_WSUM  336576     // reduced wsum_pos/neg (pad 64)
#define WS_RNORM 336640     // row norms [8192]                  -> 344832
#define WS_R2H   344832     // th2rr bf16 hi ushort[4096]        -> 346880
#define WS_R2L   346880     //                                   -> 348928
#define WS_E4    348928     // (unused in fused version)
#define WS_FH    380928     // bf16 hi ushort[8192*64] (mu overlays in place)
#define WS_FL    643072     //                                   -> 905216

__device__ __forceinline__ float waveReduceSum(float v) {
#pragma unroll
    for (int m = 32; m >= 1; m >>= 1) v += __shfl_xor(v, m, 64);
    return v;
}
__device__ __forceinline__ unsigned short f2bf(float f) {
    unsigned int u = __float_as_uint(f);
    unsigned int r = (u + 0x7fffu + ((u >> 16) & 1u)) >> 16;
    return (unsigned short)r;
}
__device__ __forceinline__ float bf2f(unsigned short h) {
    return __uint_as_float(((unsigned int)h) << 16);
}

// K1: blocks 0..511: 16 rows each -> Fh/Fl + rnorm + g/wsum partials.
//     block 512: setup math + th2rr bf16 split.  (unchanged)
__global__ __launch_bounds__(256) void k_fr(
    const float* __restrict__ A, const float* __restrict__ b, const float* __restrict__ c,
    const float* __restrict__ th1r, const float* __restrict__ th1c,
    const float* __restrict__ th2rr, const float* __restrict__ th2rc,
    const float* __restrict__ th3rr, const float* __restrict__ th3rc, const float* __restrict__ th3cr,
    const float* __restrict__ th4rr, const float* __restrict__ th4rc, const float* __restrict__ th4cr,
    const int* __restrict__ zp,
    unsigned short* __restrict__ Fh, unsigned short* __restrict__ Fl,
    unsigned short* __restrict__ R2H, unsigned short* __restrict__ R2L,
    float* __restrict__ ws)
{
    int tid = threadIdx.x, lane = tid & 63, wid = tid >> 6;

    if (blockIdx.x == 512) {
        __shared__ float fcraw[64], fz[64], sh4a[64], sh4b[64];
        int p = lane;
        int z = zp[0];
        float cv = (p < 63) ? c[p] : 0.f;
        fcraw[p] = cv;
        float av = (p < 63) ? A[z * 63 + p] : b[z];
        float s2 = waveReduceSum(av * av);
        fz[p] = av * rsqrtf(s2);
        __syncthreads();

        float t1 = 0.f, t2 = 0.f, w0 = 0.f;
#pragma unroll 8
        for (int k = 0; k < 64; k++) {
            t1 += th1r[p * 64 + k] * fz[k];
            t2 += th1c[p * 64 + k] * fz[k];
            w0 += th2rc[p * 64 + k] * fcraw[k];
        }
        ws[WS_T1R + p] = t1;
        ws[WS_T1C + p] = t2;
        ws[WS_W + p] = t1 + w0;               // w for sweep 0

        sh4a[p] = th4rr[p];
        sh4b[p] = th4rc[p];
        __syncthreads();
        float a = 0.f, bb = 0.f, g = 0.f, d = 0.f;
#pragma unroll 8
        for (int k = 0; k < 64; k++) {
            float t4 = sh4a[k];
            a  += th3rr[p * 64 + k] * fmaxf(t4, 0.f);
            bb += th3rr[p * 64 + k] * fmaxf(-t4, 0.f);
            float t5 = sh4b[k];
            g  += th3rc[p * 64 + k] * fmaxf(t5, 0.f);
            d  += th3rc[p * 64 + k] * fmaxf(-t5, 0.f);
        }
        ws[WS_AL + p] = a; ws[WS_BE + p] = bb;
        ws[WS_GA + p] = g; ws[WS_DE + p] = d;
        __syncthreads();
        sh4a[p] = th4cr[p];
        __syncthreads();
        float e1 = 0.f, e2 = 0.f;
#pragma unroll 8
        for (int k = 0; k < 64; k++) {
            float t6 = sh4a[k];
            e1 += th3cr[p * 64 + k] * fmaxf(t6, 0.f);
            e2 += th3cr[p * 64 + k] * fmaxf(-t6, 0.f);
        }
        ws[WS_ECP + p] = e1; ws[WS_ECN + p] = e2;

#pragma unroll
        for (int i = 0; i < 16; i++) {
            int idx = tid * 16 + i;
            float f = th2rr[idx];
            unsigned short h = f2bf(f);
            R2H[idx] = h;
            R2L[idx] = f2bf(f - bf2f(h));
        }
        return;
    }

    __shared__ float gsh[64];
    __shared__ float wsh2[2];
    if (tid < 64) gsh[tid] = 0.f;
    if (tid < 2) wsh2[tid] = 0.f;
    __syncthreads();

    float cv = (lane < 63) ? c[lane] : 0.f;
    float cn2 = waveReduceSum(cv * cv);
    float fcnl = cv * rsqrtf(cn2);

    int r0 = blockIdx.x * 16 + wid * 4;
    float gl = 0.f, lp = 0.f, ln = 0.f;
#pragma unroll
    for (int i = 0; i < 4; i++) {
        int r = r0 + i;
        if (r < 8000) {
            float val = (lane < 63) ? A[r * 63 + lane] : b[r];
            float s2 = waveReduceSum(val * val);
            float f = val * rsqrtf(s2);
            unsigned short h = f2bf(f);
            Fh[r * 64 + lane] = h;
            Fl[r * 64 + lane] = f2bf(f - bf2f(h));
            gl += f;
            float w = waveReduceSum(f * fcnl);
            if (lane == 0) {
                ws[WS_RNORM + r] = sqrtf(s2);
                lp += fmaxf(w, 0.f); ln += fmaxf(-w, 0.f);
            }
        } else {
            Fh[r * 64 + lane] = 0;
            Fl[r * 64 + lane] = 0;
        }
    }
    atomicAdd(&gsh[lane], gl);
    if (lane == 0) { atomicAdd(&wsh2[0], lp); atomicAdd(&wsh2[1], ln); }
    __syncthreads();
    if (tid < 64) ws[WS_GPART + blockIdx.x * 64 + tid] = gsh[tid];
    if (tid == 64) ws[WS_WPART + blockIdx.x * 2 + 0] = wsh2[0];
    if (tid == 65) ws[WS_WPART + blockIdx.x * 2 + 1] = wsh2[1];
}

// K2: plain-bf16 MFMA gram, register-resident B. (unchanged)
__global__ __launch_bounds__(256) void k_gram(
    const unsigned short* __restrict__ Fh, float* __restrict__ ws)
{
    int tid = threadIdx.x, lane = tid & 63, wid = tid >> 6;
    int m = lane & 15, quad = lane >> 4;
    int vbase = blockIdx.x * 256 + wid * 64;

    short8 AH[8];
#pragma unroll
    for (int pt = 0; pt < 4; pt++)
#pragma unroll
        for (int q = 0; q < 2; q++)
            AH[pt * 2 + q] = *(const short8*)(Fh + (vbase + pt * 16 + m) * 64 + q * 32 + quad * 8);

    float srr[16];
#pragma unroll
    for (int i = 0; i < 16; i++) srr[i] = 0.f;

    const int y = blockIdx.y;                 // u-tiles j = y + 32k, k=0..15
    const int boff = m * 64 + quad * 8;
    short8 B0[2], B1[2];
#pragma unroll
    for (int q = 0; q < 2; q++)
        B0[q] = *(const short8*)(Fh + y * 16 * 64 + boff + q * 32);

#pragma unroll 1
    for (int k2 = 0; k2 < 8; k2++) {
        int jB1 = y + 32 * (2 * k2 + 1);
#pragma unroll
        for (int q = 0; q < 2; q++)
            B1[q] = *(const short8*)(Fh + jB1 * 16 * 64 + boff + q * 32);
#pragma unroll
        for (int pt = 0; pt < 4; pt++) {
            f32x4 a = {0.f, 0.f, 0.f, 0.f};
            a = __builtin_amdgcn_mfma_f32_16x16x32_bf16(AH[pt * 2 + 0], B0[0], a, 0, 0, 0);
            a = __builtin_amdgcn_mfma_f32_16x16x32_bf16(AH[pt * 2 + 1], B0[1], a, 0, 0, 0);
#pragma unroll
            for (int r = 0; r < 4; r++) srr[pt * 4 + r] += fmaxf(a[r], 0.f);
        }
        if (k2 < 7) {
            int jB0 = y + 32 * (2 * k2 + 2);
#pragma unroll
            for (int q = 0; q < 2; q++)
                B0[q] = *(const short8*)(Fh + jB0 * 16 * 64 + boff + q * 32);
        }
#pragma unroll
        for (int pt = 0; pt < 4; pt++) {
            f32x4 a = {0.f, 0.f, 0.f, 0.f};
            a = __builtin_amdgcn_mfma_f32_16x16x32_bf16(AH[pt * 2 + 0], B1[0], a, 0, 0, 0);
            a = __builtin_amdgcn_mfma_f32_16x16x32_bf16(AH[pt * 2 + 1], B1[1], a, 0, 0, 0);
#pragma unroll
            for (int r = 0; r < 4; r++) srr[pt * 4 + r] += fmaxf(a[r], 0.f);
        }
    }
#pragma unroll
    for (int pt = 0; pt < 4; pt++)
#pragma unroll
        for (int r = 0; r < 4; r++) {
            float s = srr[pt * 4 + r];
            s += __shfl_xor(s, 1, 64); s += __shfl_xor(s, 2, 64);
            s += __shfl_xor(s, 4, 64); s += __shfl_xor(s, 8, 64);
            if (m == 0)
                ws[WS_SPART + y * 8192 + vbase + pt * 16 + quad * 4 + r] = s;
        }
}

// K3 (NEW): fused mu0 + 4 sweeps + head in ONE cooperative kernel, 125x256.
// R2H/R2L fragments + e4 live in registers for all 5 sweeps; alS..deS/wS in LDS.
// grid.sync() (with device-scope fences) replaces the 5 kernel boundaries.
__global__ __launch_bounds__(256) void k_mu_fused(
    const float* __restrict__ c,
    const float* __restrict__ th2cr, const float* __restrict__ th2rc,
    const float* __restrict__ th6r, const float* __restrict__ th6c,
    const float* __restrict__ th7, const float* __restrict__ W8,
    const float* __restrict__ b8, const int* __restrict__ zp,
    float* __restrict__ ws,
    unsigned short* __restrict__ MH, unsigned short* __restrict__ ML,
    const unsigned short* __restrict__ R2H, const unsigned short* __restrict__ R2L,
    float* __restrict__ out)
{
    cooperative_groups::grid_group grid = cooperative_groups::this_grid();

    __shared__ float XF[64][68];
    __shared__ float red[256], colp[256];
    __shared__ __align__(16) float wS[64], alS[64], beS[64], gaS[64], deS[64];
    __shared__ float fcnS[64], gS[64], sprow[64];
    __shared__ __align__(16) float e4sh[256];
    __shared__ float Ssh[64], ysh[64], feat[128];

    int tid = threadIdx.x, lane = tid & 63, wid = tid >> 6;
    int m = lane & 15, quad = lane >> 4;
    int v0 = blockIdx.x * 64;
    int cw = wid * 16 + m;
    int v = v0 + cw;
    int z = zp[0];

    // persistent A-fragments (th2rr hi/lo) — loaded ONCE for all 5 sweeps
    short8 RH[8], RL[8];
#pragma unroll
    for (int pt = 0; pt < 4; pt++)
#pragma unroll
        for (int q = 0; q < 2; q++) {
            int off = (pt * 16 + m) * 64 + q * 32 + quad * 8;
            RH[pt * 2 + q] = *(const short8*)(R2H + off);
            RL[pt * 2 + q] = *(const short8*)(R2L + off);
        }

    // ---------------- phase 0: e4 + sweep-0 mu (ex-k_mu0) ----------------
    if (wid == 0) {
        float cv = (lane < 63) ? c[lane] : 0.f;
        float cn2 = waveReduceSum(cv * cv);
        fcnS[lane] = cv * rsqrtf(cn2);
        wS[lane] = ws[WS_W + lane];
    } else if (wid == 1) {
        alS[lane] = ws[WS_AL + lane]; beS[lane] = ws[WS_BE + lane];
        float wp = 0.f;
#pragma unroll
        for (int k = 0; k < 8; k++) wp += ws[WS_WPART + (lane + 64 * k) * 2];
        wp = waveReduceSum(wp);
        if (lane == 0) ws[WS_WSUM] = wp;       // same value from every block
    } else if (wid == 2) {
        gaS[lane] = ws[WS_GA + lane]; deS[lane] = ws[WS_DE + lane];
        float wn = 0.f;
#pragma unroll
        for (int k = 0; k < 8; k++) wn += ws[WS_WPART + (lane + 64 * k) * 2 + 1];
        wn = waveReduceSum(wn);
        if (lane == 0) ws[WS_WSUM + 1] = wn;
    }
    float gv = 0.f;
#pragma unroll 8
    for (int bb = 0; bb < 128; bb++) gv += ws[WS_GPART + (wid * 128 + bb) * 64 + lane];
    red[tid] = gv;
    __syncthreads();
    if (tid < 64) gS[tid] = red[tid] + red[64 + tid] + red[128 + tid] + red[192 + tid];
    __syncthreads();
    float sv = 0.f;
#pragma unroll
    for (int y = wid * 8; y < wid * 8 + 8; y++) sv += ws[WS_SPART + y * 8192 + v0 + lane];
    red[tid] = sv;
    __syncthreads();
    if (tid < 64) sprow[tid] = red[tid] + red[64 + tid] + red[128 + tid] + red[192 + tid];
    __syncthreads();

    for (int i2 = 0; i2 < 16; i2++) {
        int i = wid * 16 + i2;
        int vr = v0 + i;
        float fr = bf2f(MH[vr * 64 + lane]) + bf2f(ML[vr * 64 + lane]);
        float dw = waveReduceSum(fr * fcnS[lane]);
        float dg = waveReduceSum(fr * gS[lane]);
        if (lane == 0) {
            float spv = sprow[i];
            float4 ee;
            ee.x = spv - 1.0f;         // remove diagonal relu(1)
            ee.y = spv - dg;           // relu(-x) = relu(x) - x
            ee.z = fmaxf(dw, 0.f);
            ee.w = fmaxf(-dw, 0.f);
            *(float4*)(&e4sh[i * 4]) = ee;     // NO global e4 round-trip anymore
        }
        XF[i][lane] = fr * ws[WS_RNORM + vr];   // mu0 row (fp32)
    }
    __syncthreads();

    short8 BH[2], BL[2];
#pragma unroll
    for (int q = 0; q < 2; q++) {
        float4 f0 = *(const float4*)(&XF[cw][q * 32 + quad * 8]);
        float4 f1 = *(const float4*)(&XF[cw][q * 32 + quad * 8 + 4]);
        float xv[8] = {f0.x, f0.y, f0.z, f0.w, f1.x, f1.y, f1.z, f1.w};
        short8 H, L;
#pragma unroll
        for (int j = 0; j < 8; j++) {
            unsigned short h = f2bf(xv[j]);
            H[j] = (short)h;
            L[j] = (short)f2bf(xv[j] - bf2f(h));
        }
        BH[q] = H; BL[q] = L;
    }
    float4 e = *(const float4*)(&e4sh[cw * 4]);   // persistent for all sweeps

    // shared mu-update core (sweep t: stores MH/ML when t<4, MUZ at t==4)
    auto mu_core = [&](const short8* BHl, const short8* BLl, int t) {
#pragma unroll
        for (int pt = 0; pt < 4; pt++) {
            f32x4 a = {0.f, 0.f, 0.f, 0.f};
#pragma unroll
            for (int q = 0; q < 2; q++) {
                a = __builtin_amdgcn_mfma_f32_16x16x32_bf16(RH[pt*2+q], BHl[q], a, 0, 0, 0);
                a = __builtin_amdgcn_mfma_f32_16x16x32_bf16(RH[pt*2+q], BLl[q], a, 0, 0, 0);
                a = __builtin_amdgcn_mfma_f32_16x16x32_bf16(RL[pt*2+q], BHl[q], a, 0, 0, 0);
            }
            int pbase = pt * 16 + quad * 4;
            float4 w4 = *(const float4*)(wS + pbase);
            float4 a4 = *(const float4*)(alS + pbase);
            float4 b4 = *(const float4*)(beS + pbase);
            float4 g4 = *(const float4*)(gaS + pbase);
            float4 d4 = *(const float4*)(deS + pbase);
            float u0 = fmaxf(a[0] + w4.x + a4.x*e.x + b4.x*e.y + g4.x*e.z + d4.x*e.w, 0.f);
            float u1 = fmaxf(a[1] + w4.y + a4.y*e.x + b4.y*e.y + g4.y*e.z + d4.y*e.w, 0.f);
            float u2 = fmaxf(a[2] + w4.z + a4.z*e.x + b4.z*e.y + g4.z*e.z + d4.z*e.w, 0.f);
            float u3 = fmaxf(a[3] + w4.w + a4.w*e.x + b4.w*e.y + g4.w*e.z + d4.w*e.w, 0.f);
            if (t < 4) {
                ushort4 h4, l4;
                h4.x = f2bf(u0); l4.x = f2bf(u0 - bf2f(h4.x));
                h4.y = f2bf(u1); l4.y = f2bf(u1 - bf2f(h4.y));
                h4.z = f2bf(u2); l4.z = f2bf(u2 - bf2f(h4.z));
                h4.w = f2bf(u3); l4.w = f2bf(u3 - bf2f(h4.w));
                *(ushort4*)(MH + v * 64 + pbase) = h4;
                *(ushort4*)(ML + v * 64 + pbase) = l4;
            }
            if (t == 4 && v == z) {
                float4 o; o.x = u0; o.y = u1; o.z = u2; o.w = u3;
                *(float4*)(ws + WS_MUZ + pbase) = o;
            }
            float c0 = u0, c1 = u1, c2 = u2, c3 = u3;
#pragma unroll
            for (int mm = 1; mm < 16; mm <<= 1) {
                c0 += __shfl_xor(c0, mm, 64);
                c1 += __shfl_xor(c1, mm, 64);
                c2 += __shfl_xor(c2, mm, 64);
                c3 += __shfl_xor(c3, mm, 64);
            }
            if (m == 0) {
                colp[wid * 64 + pbase + 0] = c0;
                colp[wid * 64 + pbase + 1] = c1;
                colp[wid * 64 + pbase + 2] = c2;
                colp[wid * 64 + pbase + 3] = c3;
            }
        }
        __syncthreads();
        if (tid < 64)
            ws[WS_CPART + t * 8000 + blockIdx.x * 64 + tid] =
                colp[tid] + colp[64 + tid] + colp[128 + tid] + colp[192 + tid];
    };

    mu_core(BH, BL, 0);

    // ---------------- sweeps 1..4 (ex-k_mu), grid.sync at boundaries ------
    for (int t = 1; t <= 4; t++) {
        __threadfence();          // release: CPART(t-1) visible device-wide
        grid.sync();
        __threadfence();          // acquire: invalidate stale L2 lines

        float s = 0.f;
        for (int blk = wid; blk < 125; blk += 4)
            s += ws[WS_CPART + (t - 1) * 8000 + blk * 64 + lane];
        red[tid] = s;
        __syncthreads();
        if (tid < 64) Ssh[tid] = red[tid] + red[64 + tid] + red[128 + tid] + red[192 + tid];
        __syncthreads();
        {
            int p = wid * 16 + m;
            float acc = 0.f;
            const float4* rowp = (const float4*)(th2cr + p * 64 + quad * 16);
#pragma unroll
            for (int kk = 0; kk < 4; kk++) {
                float4 r4 = rowp[kk];
                acc += r4.x * Ssh[quad * 16 + 4 * kk]     + r4.y * Ssh[quad * 16 + 4 * kk + 1]
                     + r4.z * Ssh[quad * 16 + 4 * kk + 2] + r4.w * Ssh[quad * 16 + 4 * kk + 3];
            }
            acc += __shfl_xor(acc, 16, 64);
            acc += __shfl_xor(acc, 32, 64);
            if (quad == 0)
                ysh[p] = fmaxf(acc + ws[WS_T1C + p] + ws[WS_WSUM] * ws[WS_ECP + p]
                               + ws[WS_WSUM + 1] * ws[WS_ECN + p], 0.f);
        }
        __syncthreads();
        {
            int p = wid * 16 + m;
            float acc = 0.f;
            const float4* rowp = (const float4*)(th2rc + p * 64 + quad * 16);
#pragma unroll
            for (int kk = 0; kk < 4; kk++) {
                float4 r4 = rowp[kk];
                acc += r4.x * ysh[quad * 16 + 4 * kk]     + r4.y * ysh[quad * 16 + 4 * kk + 1]
                     + r4.z * ysh[quad * 16 + 4 * kk + 2] + r4.w * ysh[quad * 16 + 4 * kk + 3];
            }
            acc += __shfl_xor(acc, 16, 64);
            acc += __shfl_xor(acc, 32, 64);
            if (quad == 0) wS[p] = acc + ws[WS_T1R + p];
        }
        short8 BHs[2], BLs[2];
#pragma unroll
        for (int q = 0; q < 2; q++) {
            BHs[q] = *(const short8*)(MH + v * 64 + q * 32 + quad * 8);
            BLs[q] = *(const short8*)(ML + v * 64 + q * 32 + quad * 8);
        }
        __syncthreads();
        mu_core(BHs, BLs, t);
    }

    // ---------------- head (ex-k_head), block 0 only ----------------------
    __threadfence();
    grid.sync();
    if (blockIdx.x != 0) return;
    __threadfence();

    float s = 0.f;
    for (int blk = wid; blk < 125; blk += 4)
        s += ws[WS_CPART + 4 * 8000 + blk * 64 + lane];
    red[tid] = s;
    __syncthreads();
    if (tid < 64) Ssh[tid] = red[tid] + red[64 + tid] + red[128 + tid] + red[192 + tid];
    __syncthreads();
    int p = tid;
    if (p < 64) {
        float acc = ws[WS_T1C + p] + ws[WS_WSUM] * ws[WS_ECP + p]
                  + ws[WS_WSUM + 1] * ws[WS_ECN + p];
#pragma unroll 8
        for (int k = 0; k < 64; k++) acc += th2cr[p * 64 + k] * Ssh[k];
        ysh[p] = fmaxf(acc, 0.f);
    }
    __syncthreads();
    if (p < 64) {
        float t6 = 0.f, t7 = 0.f;
#pragma unroll 8
        for (int k = 0; k < 64; k++) {
            t6 += th6r[p * 64 + k] * Ssh[k] + th6c[p * 64 + k] * ysh[k];
            t7 += th7[p * 64 + k] * ws[WS_MUZ + k];
        }
        feat[p] = 1.f / (1.f + expf(-t6));
        feat[64 + p] = 1.f / (1.f + expf(-t7));
    }
    __syncthreads();
    if (p < 2) {
        float o = b8[p];
        for (int i = 0; i < 128; i++) o += W8[p * 128 + i] * feat[i];
        out[p] = o;
    }
}

extern "C" void kernel_launch(void* const* d_in, const int* in_sizes, int n_in,
                              void* d_out, int out_size, void* d_ws, size_t ws_size,
                              hipStream_t stream) {
    (void)in_sizes; (void)n_in; (void)out_size; (void)ws_size;
    const float* A     = (const float*)d_in[0];
    const float* b     = (const float*)d_in[1];
    const float* c     = (const float*)d_in[2];
    const float* th1r  = (const float*)d_in[3];
    const float* th1c  = (const float*)d_in[4];
    const float* th2rr = (const float*)d_in[5];
    const float* th2rc = (const float*)d_in[6];
    const float* th2cr = (const float*)d_in[7];
    const float* th3rr = (const float*)d_in[8];
    const float* th3rc = (const float*)d_in[9];
    const float* th3cr = (const float*)d_in[10];
    const float* th4rr = (const float*)d_in[11];
    const float* th4rc = (const float*)d_in[12];
    const float* th4cr = (const float*)d_in[13];
    const float* th6r  = (const float*)d_in[14];
    const float* th6c  = (const float*)d_in[15];
    const float* th7   = (const float*)d_in[16];
    const float* W8    = (const float*)d_in[17];
    const float* b8    = (const float*)d_in[18];
    const int*   zp    = (const int*)d_in[19];
    float* ws  = (float*)d_ws;
    float* out = (float*)d_out;
    unsigned short* Fh  = (unsigned short*)(ws + WS_FH);
    unsigned short* Fl  = (unsigned short*)(ws + WS_FL);
    unsigned short* R2H = (unsigned short*)(ws + WS_R2H);
    unsigned short* R2L = (unsigned short*)(ws + WS_R2L);

    k_fr<<<513, 256, 0, stream>>>(A, b, c, th1r, th1c, th2rr, th2rc, th3rr, th3rc,
                                  th3cr, th4rr, th4rc, th4cr, zp, Fh, Fl, R2H, R2L, ws);
    k_gram<<<dim3(32, 32), 256, 0, stream>>>(Fh, ws);
    {
        void* kargs[] = {
            (void*)&c, (void*)&th2cr, (void*)&th2rc, (void*)&th6r, (void*)&th6c,
            (void*)&th7, (void*)&W8, (void*)&b8, (void*)&zp, (void*)&ws,
            (void*)&Fh, (void*)&Fl, (void*)&R2H, (void*)&R2L, (void*)&out };
        hipLaunchCooperativeKernel((const void*)k_mu_fused, dim3(125), dim3(256),
                                   kargs, 0, stream);
    }
}

// Round 2
// 260.701 us; speedup vs baseline: 1.5658x; 1.5658x over previous
//
#include <hip/hip_runtime.h>
#include <math.h>

typedef __attribute__((ext_vector_type(8))) short short8;
typedef __attribute__((ext_vector_type(4))) float f32x4;

// ---- workspace layout (float offsets) ---- total 905216 floats = 3.62 MB
#define WS_SPART 0          // srr partials [32][8192]           -> 262144
#define WS_GPART 262144     // g partials [512][64]              -> 294912
#define WS_WPART 294912     // wsum partials [512][2]            -> 295936
#define WS_CPART 295936     // colsum partials [5][125*64]       -> 335936
#define WS_T1R   335936
#define WS_T1C   336000
#define WS_AL    336064
#define WS_BE    336128
#define WS_GA    336192
#define WS_DE    336256
#define WS_ECP   336320
#define WS_ECN   336384
#define WS_W     336448     // w for sweep 0 only
#define WS_MUZ   336512
#define WS_WSUM  336576     // reduced wsum_pos/neg (pad 64)
#define WS_RNORM 336640     // row norms [8192]                  -> 344832
#define WS_R2H   344832     // th2rr bf16 hi ushort[4096]        -> 346880
#define WS_R2L   346880     //                                   -> 348928
#define WS_CNT   348928     // spin-barrier counters int[8]
#define WS_FH    380928     // bf16 hi ushort[8192*64]
#define WS_FL    643072     //                                   -> 905216

#define NBLK 125

#define ALDF(p)    __hip_atomic_load((p), __ATOMIC_RELAXED, __HIP_MEMORY_SCOPE_AGENT)
#define ASTF(p, x) __hip_atomic_store((p), (x), __ATOMIC_RELAXED, __HIP_MEMORY_SCOPE_AGENT)

__device__ __forceinline__ float waveReduceSum(float v) {
#pragma unroll
    for (int m = 32; m >= 1; m >>= 1) v += __shfl_xor(v, m, 64);
    return v;
}
__device__ __forceinline__ unsigned short f2bf(float f) {
    unsigned int u = __float_as_uint(f);
    unsigned int r = (u + 0x7fffu + ((u >> 16) & 1u)) >> 16;
    return (unsigned short)r;
}
__device__ __forceinline__ float bf2f(unsigned short h) {
    return __uint_as_float(((unsigned int)h) << 16);
}

// K1: blocks 0..511: 16 rows each -> Fh/Fl + rnorm + g/wsum partials.
//     block 512: setup math + th2rr bf16 split + barrier-counter zero.
__global__ __launch_bounds__(256) void k_fr(
    const float* __restrict__ A, const float* __restrict__ b, const float* __restrict__ c,
    const float* __restrict__ th1r, const float* __restrict__ th1c,
    const float* __restrict__ th2rr, const float* __restrict__ th2rc,
    const float* __restrict__ th3rr, const float* __restrict__ th3rc, const float* __restrict__ th3cr,
    const float* __restrict__ th4rr, const float* __restrict__ th4rc, const float* __restrict__ th4cr,
    const int* __restrict__ zp,
    unsigned short* __restrict__ Fh, unsigned short* __restrict__ Fl,
    unsigned short* __restrict__ R2H, unsigned short* __restrict__ R2L,
    float* __restrict__ ws)
{
    int tid = threadIdx.x, lane = tid & 63, wid = tid >> 6;

    if (blockIdx.x == 512) {
        __shared__ float fcraw[64], fz[64], sh4a[64], sh4b[64];
        int p = lane;
        int z = zp[0];
        float cv = (p < 63) ? c[p] : 0.f;
        fcraw[p] = cv;
        float av = (p < 63) ? A[z * 63 + p] : b[z];
        float s2 = waveReduceSum(av * av);
        fz[p] = av * rsqrtf(s2);
        __syncthreads();

        float t1 = 0.f, t2 = 0.f, w0 = 0.f;
#pragma unroll 8
        for (int k = 0; k < 64; k++) {
            t1 += th1r[p * 64 + k] * fz[k];
            t2 += th1c[p * 64 + k] * fz[k];
            w0 += th2rc[p * 64 + k] * fcraw[k];
        }
        ws[WS_T1R + p] = t1;
        ws[WS_T1C + p] = t2;
        ws[WS_W + p] = t1 + w0;               // w for sweep 0

        sh4a[p] = th4rr[p];
        sh4b[p] = th4rc[p];
        __syncthreads();
        float a = 0.f, bb = 0.f, g = 0.f, d = 0.f;
#pragma unroll 8
        for (int k = 0; k < 64; k++) {
            float t4 = sh4a[k];
            a  += th3rr[p * 64 + k] * fmaxf(t4, 0.f);
            bb += th3rr[p * 64 + k] * fmaxf(-t4, 0.f);
            float t5 = sh4b[k];
            g  += th3rc[p * 64 + k] * fmaxf(t5, 0.f);
            d  += th3rc[p * 64 + k] * fmaxf(-t5, 0.f);
        }
        ws[WS_AL + p] = a; ws[WS_BE + p] = bb;
        ws[WS_GA + p] = g; ws[WS_DE + p] = d;
        __syncthreads();
        sh4a[p] = th4cr[p];
        __syncthreads();
        float e1 = 0.f, e2 = 0.f;
#pragma unroll 8
        for (int k = 0; k < 64; k++) {
            float t6 = sh4a[k];
            e1 += th3cr[p * 64 + k] * fmaxf(t6, 0.f);
            e2 += th3cr[p * 64 + k] * fmaxf(-t6, 0.f);
        }
        ws[WS_ECP + p] = e1; ws[WS_ECN + p] = e2;

        if (tid < 8) ((int*)(ws + WS_CNT))[tid] = 0;   // spin-barrier counters

#pragma unroll
        for (int i = 0; i < 16; i++) {
            int idx = tid * 16 + i;
            float f = th2rr[idx];
            unsigned short h = f2bf(f);
            R2H[idx] = h;
            R2L[idx] = f2bf(f - bf2f(h));
        }
        return;
    }

    __shared__ float gsh[64];
    __shared__ float wsh2[2];
    if (tid < 64) gsh[tid] = 0.f;
    if (tid < 2) wsh2[tid] = 0.f;
    __syncthreads();

    float cv = (lane < 63) ? c[lane] : 0.f;
    float cn2 = waveReduceSum(cv * cv);
    float fcnl = cv * rsqrtf(cn2);

    int r0 = blockIdx.x * 16 + wid * 4;
    float gl = 0.f, lp = 0.f, ln = 0.f;
#pragma unroll
    for (int i = 0; i < 4; i++) {
        int r = r0 + i;
        if (r < 8000) {
            float val = (lane < 63) ? A[r * 63 + lane] : b[r];
            float s2 = waveReduceSum(val * val);
            float f = val * rsqrtf(s2);
            unsigned short h = f2bf(f);
            Fh[r * 64 + lane] = h;
            Fl[r * 64 + lane] = f2bf(f - bf2f(h));
            gl += f;
            float w = waveReduceSum(f * fcnl);
            if (lane == 0) {
                ws[WS_RNORM + r] = sqrtf(s2);
                lp += fmaxf(w, 0.f); ln += fmaxf(-w, 0.f);
            }
        } else {
            Fh[r * 64 + lane] = 0;
            Fl[r * 64 + lane] = 0;
        }
    }
    atomicAdd(&gsh[lane], gl);
    if (lane == 0) { atomicAdd(&wsh2[0], lp); atomicAdd(&wsh2[1], ln); }
    __syncthreads();
    if (tid < 64) ws[WS_GPART + blockIdx.x * 64 + tid] = gsh[tid];
    if (tid == 64) ws[WS_WPART + blockIdx.x * 2 + 0] = wsh2[0];
    if (tid == 65) ws[WS_WPART + blockIdx.x * 2 + 1] = wsh2[1];
}

// K2: plain-bf16 MFMA gram, register-resident B. (unchanged)
__global__ __launch_bounds__(256) void k_gram(
    const unsigned short* __restrict__ Fh, float* __restrict__ ws)
{
    int tid = threadIdx.x, lane = tid & 63, wid = tid >> 6;
    int m = lane & 15, quad = lane >> 4;
    int vbase = blockIdx.x * 256 + wid * 64;

    short8 AH[8];
#pragma unroll
    for (int pt = 0; pt < 4; pt++)
#pragma unroll
        for (int q = 0; q < 2; q++)
            AH[pt * 2 + q] = *(const short8*)(Fh + (vbase + pt * 16 + m) * 64 + q * 32 + quad * 8);

    float srr[16];
#pragma unroll
    for (int i = 0; i < 16; i++) srr[i] = 0.f;

    const int y = blockIdx.y;                 // u-tiles j = y + 32k, k=0..15
    const int boff = m * 64 + quad * 8;
    short8 B0[2], B1[2];
#pragma unroll
    for (int q = 0; q < 2; q++)
        B0[q] = *(const short8*)(Fh + y * 16 * 64 + boff + q * 32);

#pragma unroll 1
    for (int k2 = 0; k2 < 8; k2++) {
        int jB1 = y + 32 * (2 * k2 + 1);
#pragma unroll
        for (int q = 0; q < 2; q++)
            B1[q] = *(const short8*)(Fh + jB1 * 16 * 64 + boff + q * 32);
#pragma unroll
        for (int pt = 0; pt < 4; pt++) {
            f32x4 a = {0.f, 0.f, 0.f, 0.f};
            a = __builtin_amdgcn_mfma_f32_16x16x32_bf16(AH[pt * 2 + 0], B0[0], a, 0, 0, 0);
            a = __builtin_amdgcn_mfma_f32_16x16x32_bf16(AH[pt * 2 + 1], B0[1], a, 0, 0, 0);
#pragma unroll
            for (int r = 0; r < 4; r++) srr[pt * 4 + r] += fmaxf(a[r], 0.f);
        }
        if (k2 < 7) {
            int jB0 = y + 32 * (2 * k2 + 2);
#pragma unroll
            for (int q = 0; q < 2; q++)
                B0[q] = *(const short8*)(Fh + jB0 * 16 * 64 + boff + q * 32);
        }
#pragma unroll
        for (int pt = 0; pt < 4; pt++) {
            f32x4 a = {0.f, 0.f, 0.f, 0.f};
            a = __builtin_amdgcn_mfma_f32_16x16x32_bf16(AH[pt * 2 + 0], B1[0], a, 0, 0, 0);
            a = __builtin_amdgcn_mfma_f32_16x16x32_bf16(AH[pt * 2 + 1], B1[1], a, 0, 0, 0);
#pragma unroll
            for (int r = 0; r < 4; r++) srr[pt * 4 + r] += fmaxf(a[r], 0.f);
        }
    }
#pragma unroll
    for (int pt = 0; pt < 4; pt++)
#pragma unroll
        for (int r = 0; r < 4; r++) {
            float s = srr[pt * 4 + r];
            s += __shfl_xor(s, 1, 64); s += __shfl_xor(s, 2, 64);
            s += __shfl_xor(s, 4, 64); s += __shfl_xor(s, 8, 64);
            if (m == 0)
                ws[WS_SPART + y * 8192 + vbase + pt * 16 + quad * 4 + r] = s;
        }
}

// K3: fused mu0 + 4 sweeps + head, ONE cooperative kernel, 125x256.
// NO grid.sync / threadfence: all cross-block data moves via agent-scope
// RELAXED atomics (point-coherent, no L2 wb/inv); barrier = atomic counter
// spin. mu state lives in LDS (padded ushort[64][72] hi/lo) across sweeps.
__global__ __launch_bounds__(256) void k_mu_fused(
    const float* __restrict__ c,
    const float* __restrict__ th2cr, const float* __restrict__ th2rc,
    const float* __restrict__ th6r, const float* __restrict__ th6c,
    const float* __restrict__ th7, const float* __restrict__ W8,
    const float* __restrict__ b8, const int* __restrict__ zp,
    float* __restrict__ ws,
    const unsigned short* __restrict__ Fh, const unsigned short* __restrict__ Fl,
    const unsigned short* __restrict__ R2H, const unsigned short* __restrict__ R2L,
    float* __restrict__ out)
{
    __shared__ float XF[64][68];
    __shared__ unsigned short UHT[64][72], ULT[64][72];   // mu state, padded
    __shared__ float red[256], colp[256];
    __shared__ __align__(16) float wS[64], alS[64], beS[64], gaS[64], deS[64];
    __shared__ float fcnS[64], gS[64], sprow[64];
    __shared__ __align__(16) float e4sh[256];
    __shared__ float Ssh[64], ysh[64], feat[128];

    int tid = threadIdx.x, lane = tid & 63, wid = tid >> 6;
    int m = lane & 15, quad = lane >> 4;
    int v0 = blockIdx.x * 64;
    int cw = wid * 16 + m;
    int v = v0 + cw;
    int z = zp[0];
    int* cnt = (int*)(ws + WS_CNT);

    // persistent A-fragments (th2rr hi/lo) — loaded ONCE for all 5 sweeps
    short8 RH[8], RL[8];
#pragma unroll
    for (int pt = 0; pt < 4; pt++)
#pragma unroll
        for (int q = 0; q < 2; q++) {
            int off = (pt * 16 + m) * 64 + q * 32 + quad * 8;
            RH[pt * 2 + q] = *(const short8*)(R2H + off);
            RL[pt * 2 + q] = *(const short8*)(R2L + off);
        }

    // ---------------- phase 0: e4 + mu0 prep ----------------
    if (wid == 0) {
        float cv = (lane < 63) ? c[lane] : 0.f;
        float cn2 = waveReduceSum(cv * cv);
        fcnS[lane] = cv * rsqrtf(cn2);
        wS[lane] = ws[WS_W + lane];
    } else if (wid == 1) {
        alS[lane] = ws[WS_AL + lane]; beS[lane] = ws[WS_BE + lane];
        float wp = 0.f;
#pragma unroll
        for (int k = 0; k < 8; k++) wp += ws[WS_WPART + (lane + 64 * k) * 2];
        wp = waveReduceSum(wp);
        if (lane == 0) ws[WS_WSUM] = wp;       // same value from every block
    } else if (wid == 2) {
        gaS[lane] = ws[WS_GA + lane]; deS[lane] = ws[WS_DE + lane];
        float wn = 0.f;
#pragma unroll
        for (int k = 0; k < 8; k++) wn += ws[WS_WPART + (lane + 64 * k) * 2 + 1];
        wn = waveReduceSum(wn);
        if (lane == 0) ws[WS_WSUM + 1] = wn;
    }
    float gv = 0.f;
#pragma unroll 8
    for (int bb = 0; bb < 128; bb++) gv += ws[WS_GPART + (wid * 128 + bb) * 64 + lane];
    red[tid] = gv;
    __syncthreads();
    if (tid < 64) gS[tid] = red[tid] + red[64 + tid] + red[128 + tid] + red[192 + tid];
    __syncthreads();
    float sv = 0.f;
#pragma unroll
    for (int y = wid * 8; y < wid * 8 + 8; y++) sv += ws[WS_SPART + y * 8192 + v0 + lane];
    red[tid] = sv;
    __syncthreads();
    if (tid < 64) sprow[tid] = red[tid] + red[64 + tid] + red[128 + tid] + red[192 + tid];
    __syncthreads();

    for (int i2 = 0; i2 < 16; i2++) {
        int i = wid * 16 + i2;
        int vr = v0 + i;
        float fr = bf2f(Fh[vr * 64 + lane]) + bf2f(Fl[vr * 64 + lane]);
        float dw = waveReduceSum(fr * fcnS[lane]);
        float dg = waveReduceSum(fr * gS[lane]);
        if (lane == 0) {
            float spv = sprow[i];
            float4 ee;
            ee.x = spv - 1.0f;         // remove diagonal relu(1)
            ee.y = spv - dg;           // relu(-x) = relu(x) - x
            ee.z = fmaxf(dw, 0.f);
            ee.w = fmaxf(-dw, 0.f);
            *(float4*)(&e4sh[i * 4]) = ee;
        }
        XF[i][lane] = fr * ws[WS_RNORM + vr];   // mu0 row (fp32)
    }
    __syncthreads();

    short8 BH[2], BL[2];
#pragma unroll
    for (int q = 0; q < 2; q++) {
        float4 f0 = *(const float4*)(&XF[cw][q * 32 + quad * 8]);
        float4 f1 = *(const float4*)(&XF[cw][q * 32 + quad * 8 + 4]);
        float xv[8] = {f0.x, f0.y, f0.z, f0.w, f1.x, f1.y, f1.z, f1.w};
        short8 H, L;
#pragma unroll
        for (int j = 0; j < 8; j++) {
            unsigned short h = f2bf(xv[j]);
            H[j] = (short)h;
            L[j] = (short)f2bf(xv[j] - bf2f(h));
        }
        BH[q] = H; BL[q] = L;
    }
    float4 e = *(const float4*)(&e4sh[cw * 4]);   // persistent for all sweeps

    // ---------------- sweeps 0..4 ----------------
    for (int t = 0; t < 5; t++) {
        if (t > 0) {
            // Ssh = reduce CPART(t-1) — same fixed order as 6-kernel version
            float s = 0.f;
            for (int blk = wid; blk < NBLK; blk += 4)
                s += ALDF(&ws[WS_CPART + (t - 1) * 8000 + blk * 64 + lane]);
            red[tid] = s;
            __syncthreads();
            if (tid < 64) Ssh[tid] = red[tid] + red[64 + tid] + red[128 + tid] + red[192 + tid];
            __syncthreads();
            {
                int p = wid * 16 + m;
                float acc = 0.f;
                const float4* rowp = (const float4*)(th2cr + p * 64 + quad * 16);
#pragma unroll
                for (int kk = 0; kk < 4; kk++) {
                    float4 r4 = rowp[kk];
                    acc += r4.x * Ssh[quad * 16 + 4 * kk]     + r4.y * Ssh[quad * 16 + 4 * kk + 1]
                         + r4.z * Ssh[quad * 16 + 4 * kk + 2] + r4.w * Ssh[quad * 16 + 4 * kk + 3];
                }
                acc += __shfl_xor(acc, 16, 64);
                acc += __shfl_xor(acc, 32, 64);
                if (quad == 0)
                    ysh[p] = fmaxf(acc + ws[WS_T1C + p] + ws[WS_WSUM] * ws[WS_ECP + p]
                                   + ws[WS_WSUM + 1] * ws[WS_ECN + p], 0.f);
            }
            __syncthreads();
            {
                int p = wid * 16 + m;
                float acc = 0.f;
                const float4* rowp = (const float4*)(th2rc + p * 64 + quad * 16);
#pragma unroll
                for (int kk = 0; kk < 4; kk++) {
                    float4 r4 = rowp[kk];
                    acc += r4.x * ysh[quad * 16 + 4 * kk]     + r4.y * ysh[quad * 16 + 4 * kk + 1]
                         + r4.z * ysh[quad * 16 + 4 * kk + 2] + r4.w * ysh[quad * 16 + 4 * kk + 3];
                }
                acc += __shfl_xor(acc, 16, 64);
                acc += __shfl_xor(acc, 32, 64);
                if (quad == 0) wS[p] = acc + ws[WS_T1R + p];
            }
            // mu(t-1) fragments from LDS state
#pragma unroll
            for (int q = 0; q < 2; q++) {
                BH[q] = *(const short8*)(&UHT[cw][q * 32 + quad * 8]);
                BL[q] = *(const short8*)(&ULT[cw][q * 32 + quad * 8]);
            }
        }
        __syncthreads();   // wS ready; UHT reads done before overwrite

#pragma unroll
        for (int pt = 0; pt < 4; pt++) {
            f32x4 a = {0.f, 0.f, 0.f, 0.f};
#pragma unroll
            for (int q = 0; q < 2; q++) {
                a = __builtin_amdgcn_mfma_f32_16x16x32_bf16(RH[pt*2+q], BH[q], a, 0, 0, 0);
                a = __builtin_amdgcn_mfma_f32_16x16x32_bf16(RH[pt*2+q], BL[q], a, 0, 0, 0);
                a = __builtin_amdgcn_mfma_f32_16x16x32_bf16(RL[pt*2+q], BH[q], a, 0, 0, 0);
            }
            int pbase = pt * 16 + quad * 4;
            float4 w4 = *(const float4*)(wS + pbase);
            float4 a4 = *(const float4*)(alS + pbase);
            float4 b4 = *(const float4*)(beS + pbase);
            float4 g4 = *(const float4*)(gaS + pbase);
            float4 d4 = *(const float4*)(deS + pbase);
            float u0 = fmaxf(a[0] + w4.x + a4.x*e.x + b4.x*e.y + g4.x*e.z + d4.x*e.w, 0.f);
            float u1 = fmaxf(a[1] + w4.y + a4.y*e.x + b4.y*e.y + g4.y*e.z + d4.y*e.w, 0.f);
            float u2 = fmaxf(a[2] + w4.z + a4.z*e.x + b4.z*e.y + g4.z*e.z + d4.z*e.w, 0.f);
            float u3 = fmaxf(a[3] + w4.w + a4.w*e.x + b4.w*e.y + g4.w*e.z + d4.w*e.w, 0.f);
            if (t < 4) {
                ushort4 h4, l4;
                h4.x = f2bf(u0); l4.x = f2bf(u0 - bf2f(h4.x));
                h4.y = f2bf(u1); l4.y = f2bf(u1 - bf2f(h4.y));
                h4.z = f2bf(u2); l4.z = f2bf(u2 - bf2f(h4.z));
                h4.w = f2bf(u3); l4.w = f2bf(u3 - bf2f(h4.w));
                *(ushort4*)(&UHT[cw][pbase]) = h4;
                *(ushort4*)(&ULT[cw][pbase]) = l4;
            } else if (v == z) {
                ASTF(&ws[WS_MUZ + pbase + 0], u0);
                ASTF(&ws[WS_MUZ + pbase + 1], u1);
                ASTF(&ws[WS_MUZ + pbase + 2], u2);
                ASTF(&ws[WS_MUZ + pbase + 3], u3);
            }
            float c0 = u0, c1 = u1, c2 = u2, c3 = u3;
#pragma unroll
            for (int mm = 1; mm < 16; mm <<= 1) {
                c0 += __shfl_xor(c0, mm, 64);
                c1 += __shfl_xor(c1, mm, 64);
                c2 += __shfl_xor(c2, mm, 64);
                c3 += __shfl_xor(c3, mm, 64);
            }
            if (m == 0) {
                colp[wid * 64 + pbase + 0] = c0;
                colp[wid * 64 + pbase + 1] = c1;
                colp[wid * 64 + pbase + 2] = c2;
                colp[wid * 64 + pbase + 3] = c3;
            }
        }
        __syncthreads();
        if (tid < 64)
            ASTF(&ws[WS_CPART + t * 8000 + blockIdx.x * 64 + tid],
                 colp[tid] + colp[64 + tid] + colp[128 + tid] + colp[192 + tid]);

        // ---- fence-free global barrier: syncthreads drains the atomic
        // stores (s_waitcnt vmcnt(0) before s_barrier), then counter spin.
        __syncthreads();
        if (tid == 0) {
            __hip_atomic_fetch_add(&cnt[t], 1, __ATOMIC_RELAXED, __HIP_MEMORY_SCOPE_AGENT);
            while (__hip_atomic_load(&cnt[t], __ATOMIC_RELAXED, __HIP_MEMORY_SCOPE_AGENT) < NBLK)
                __builtin_amdgcn_s_sleep(2);
        }
        __syncthreads();
    }

    // ---------------- head (block 0 only) ----------------
    if (blockIdx.x != 0) return;

    float s = 0.f;
    for (int blk = wid; blk < NBLK; blk += 4)
        s += ALDF(&ws[WS_CPART + 4 * 8000 + blk * 64 + lane]);
    red[tid] = s;
    __syncthreads();
    if (tid < 64) Ssh[tid] = red[tid] + red[64 + tid] + red[128 + tid] + red[192 + tid];
    __syncthreads();
    int p = tid;
    if (p < 64) {
        float acc = ws[WS_T1C + p] + ws[WS_WSUM] * ws[WS_ECP + p]
                  + ws[WS_WSUM + 1] * ws[WS_ECN + p];
#pragma unroll 8
        for (int k = 0; k < 64; k++) acc += th2cr[p * 64 + k] * Ssh[k];
        ysh[p] = fmaxf(acc, 0.f);
    }
    __syncthreads();
    if (p < 64) {
        float t6 = 0.f, t7 = 0.f;
#pragma unroll 8
        for (int k = 0; k < 64; k++) {
            t6 += th6r[p * 64 + k] * Ssh[k] + th6c[p * 64 + k] * ysh[k];
            t7 += th7[p * 64 + k] * ALDF(&ws[WS_MUZ + k]);
        }
        feat[p] = 1.f / (1.f + expf(-t6));
        feat[64 + p] = 1.f / (1.f + expf(-t7));
    }
    __syncthreads();
    if (p < 2) {
        float o = b8[p];
        for (int i = 0; i < 128; i++) o += W8[p * 128 + i] * feat[i];
        out[p] = o;
    }
}

extern "C" void kernel_launch(void* const* d_in, const int* in_sizes, int n_in,
                              void* d_out, int out_size, void* d_ws, size_t ws_size,
                              hipStream_t stream) {
    (void)in_sizes; (void)n_in; (void)out_size; (void)ws_size;
    const float* A     = (const float*)d_in[0];
    const float* b     = (const float*)d_in[1];
    const float* c     = (const float*)d_in[2];
    const float* th1r  = (const float*)d_in[3];
    const float* th1c  = (const float*)d_in[4];
    const float* th2rr = (const float*)d_in[5];
    const float* th2rc = (const float*)d_in[6];
    const float* th2cr = (const float*)d_in[7];
    const float* th3rr = (const float*)d_in[8];
    const float* th3rc = (const float*)d_in[9];
    const float* th3cr = (const float*)d_in[10];
    const float* th4rr = (const float*)d_in[11];
    const float* th4rc = (const float*)d_in[12];
    const float* th4cr = (const float*)d_in[13];
    const float* th6r  = (const float*)d_in[14];
    const float* th6c  = (const float*)d_in[15];
    const float* th7   = (const float*)d_in[16];
    const float* W8    = (const float*)d_in[17];
    const float* b8    = (const float*)d_in[18];
    const int*   zp    = (const int*)d_in[19];
    float* ws  = (float*)d_ws;
    float* out = (float*)d_out;
    unsigned short* Fh  = (unsigned short*)(ws + WS_FH);
    unsigned short* Fl  = (unsigned short*)(ws + WS_FL);
    unsigned short* R2H = (unsigned short*)(ws + WS_R2H);
    unsigned short* R2L = (unsigned short*)(ws + WS_R2L);

    k_fr<<<513, 256, 0, stream>>>(A, b, c, th1r, th1c, th2rr, th2rc, th3rr, th3rc,
                                  th3cr, th4rr, th4rc, th4cr, zp, Fh, Fl, R2H, R2L, ws);
    k_gram<<<dim3(32, 32), 256, 0, stream>>>(Fh, ws);
    {
        const unsigned short* Fhc = Fh;
        const unsigned short* Flc = Fl;
        const unsigned short* R2Hc = R2H;
        const unsigned short* R2Lc = R2L;
        void* kargs[] = {
            (void*)&c, (void*)&th2cr, (void*)&th2rc, (void*)&th6r, (void*)&th6c,
            (void*)&th7, (void*)&W8, (void*)&b8, (void*)&zp, (void*)&ws,
            (void*)&Fhc, (void*)&Flc, (void*)&R2Hc, (void*)&R2Lc, (void*)&out };
        hipLaunchCooperativeKernel((const void*)k_mu_fused, dim3(NBLK), dim3(256),
                                   kargs, 0, stream);
    }
}

// Round 3
// 234.915 us; speedup vs baseline: 1.7376x; 1.1098x over previous
//
#include <hip/hip_runtime.h>
#include <math.h>

typedef __attribute__((ext_vector_type(8))) short short8;
typedef __attribute__((ext_vector_type(4))) float f32x4;

// ---- workspace layout (float offsets) ---- total 905216 floats = 3.62 MB
#define WS_SPART 0          // srr partials [32][8192]           -> 262144
#define WS_GPART 262144     // g partials [512][64]              -> 294912
#define WS_WPART 294912     // wsum partials [512][2]            -> 295936
#define WS_CPART 295936     // colsum partials [5][128*64] (PADDED) -> 336896
#define WS_T1R   336896
#define WS_T1C   336960
#define WS_AL    337024
#define WS_BE    337088
#define WS_GA    337152
#define WS_DE    337216
#define WS_ECP   337280
#define WS_ECN   337344
#define WS_W     337408     // w for sweep 0 only
#define WS_MUZ   337472
#define WS_WSUM  337536     // reduced wsum_pos/neg (pad 64)
#define WS_RNORM 337600     // row norms [8192]                  -> 345792
#define WS_R2H   345792     // th2rr bf16 hi ushort[4096]        -> 347840
#define WS_R2L   347840     //                                   -> 349888
#define WS_CNT   349888     // barrier: arrivals int[8] + release int[8]
#define WS_FH    380928     // bf16 hi ushort[8192*64]
#define WS_FL    643072     //                                   -> 905216

#define NBLK 125

__device__ __forceinline__ float waveReduceSum(float v) {
#pragma unroll
    for (int m = 32; m >= 1; m >>= 1) v += __shfl_xor(v, m, 64);
    return v;
}
__device__ __forceinline__ unsigned short f2bf(float f) {
    unsigned int u = __float_as_uint(f);
    unsigned int r = (u + 0x7fffu + ((u >> 16) & 1u)) >> 16;
    return (unsigned short)r;
}
__device__ __forceinline__ float bf2f(unsigned short h) {
    return __uint_as_float(((unsigned int)h) << 16);
}

// Batched coherent (L1+L2-bypass) strided sum: 32 loads in flight, ONE wait.
// Sum order = ascending i, identical to the old serial ALDF loop.
__device__ __forceinline__ float sum32_coherent(const float* base) {
    float v[32];
#pragma unroll
    for (int i = 0; i < 32; i++)
        asm volatile("global_load_dword %0, %1, off sc0 sc1"
                     : "=v"(v[i]) : "v"(base + i * 256));
    asm volatile("s_waitcnt vmcnt(0)" ::: "memory");
    __builtin_amdgcn_sched_barrier(0);
    float s = 0.f;
#pragma unroll
    for (int i = 0; i < 32; i++) s += v[i];
    return s;
}

// K1: blocks 0..511: 16 rows each -> Fh/Fl + rnorm + g/wsum partials.
//     block 512: setup math + th2rr bf16 split + barrier/pad zeroing.
__global__ __launch_bounds__(256) void k_fr(
    const float* __restrict__ A, const float* __restrict__ b, const float* __restrict__ c,
    const float* __restrict__ th1r, const float* __restrict__ th1c,
    const float* __restrict__ th2rr, const float* __restrict__ th2rc,
    const float* __restrict__ th3rr, const float* __restrict__ th3rc, const float* __restrict__ th3cr,
    const float* __restrict__ th4rr, const float* __restrict__ th4rc, const float* __restrict__ th4cr,
    const int* __restrict__ zp,
    unsigned short* __restrict__ Fh, unsigned short* __restrict__ Fl,
    unsigned short* __restrict__ R2H, unsigned short* __restrict__ R2L,
    float* __restrict__ ws)
{
    int tid = threadIdx.x, lane = tid & 63, wid = tid >> 6;

    if (blockIdx.x == 512) {
        __shared__ float fcraw[64], fz[64], sh4a[64], sh4b[64];
        int p = lane;
        int z = zp[0];
        float cv = (p < 63) ? c[p] : 0.f;
        fcraw[p] = cv;
        float av = (p < 63) ? A[z * 63 + p] : b[z];
        float s2 = waveReduceSum(av * av);
        fz[p] = av * rsqrtf(s2);
        __syncthreads();

        float t1 = 0.f, t2 = 0.f, w0 = 0.f;
#pragma unroll 8
        for (int k = 0; k < 64; k++) {
            t1 += th1r[p * 64 + k] * fz[k];
            t2 += th1c[p * 64 + k] * fz[k];
            w0 += th2rc[p * 64 + k] * fcraw[k];
        }
        ws[WS_T1R + p] = t1;
        ws[WS_T1C + p] = t2;
        ws[WS_W + p] = t1 + w0;               // w for sweep 0

        sh4a[p] = th4rr[p];
        sh4b[p] = th4rc[p];
        __syncthreads();
        float a = 0.f, bb = 0.f, g = 0.f, d = 0.f;
#pragma unroll 8
        for (int k = 0; k < 64; k++) {
            float t4 = sh4a[k];
            a  += th3rr[p * 64 + k] * fmaxf(t4, 0.f);
            bb += th3rr[p * 64 + k] * fmaxf(-t4, 0.f);
            float t5 = sh4b[k];
            g  += th3rc[p * 64 + k] * fmaxf(t5, 0.f);
            d  += th3rc[p * 64 + k] * fmaxf(-t5, 0.f);
        }
        ws[WS_AL + p] = a; ws[WS_BE + p] = bb;
        ws[WS_GA + p] = g; ws[WS_DE + p] = d;
        __syncthreads();
        sh4a[p] = th4cr[p];
        __syncthreads();
        float e1 = 0.f, e2 = 0.f;
#pragma unroll 8
        for (int k = 0; k < 64; k++) {
            float t6 = sh4a[k];
            e1 += th3cr[p * 64 + k] * fmaxf(t6, 0.f);
            e2 += th3cr[p * 64 + k] * fmaxf(-t6, 0.f);
        }
        ws[WS_ECP + p] = e1; ws[WS_ECN + p] = e2;

        if (tid < 16) ((int*)(ws + WS_CNT))[tid] = 0;   // arrivals + release flags
        // zero CPART pad rows (blk 125..127) for all 5 sweeps: +0.0f in the
        // padded batched sum is bit-exact (all colp sums are >= +0)
        if (tid < 192) {
#pragma unroll
            for (int t5 = 0; t5 < 5; t5++)
                ws[WS_CPART + t5 * 8192 + 8000 + tid] = 0.f;
        }

#pragma unroll
        for (int i = 0; i < 16; i++) {
            int idx = tid * 16 + i;
            float f = th2rr[idx];
            unsigned short h = f2bf(f);
            R2H[idx] = h;
            R2L[idx] = f2bf(f - bf2f(h));
        }
        return;
    }

    __shared__ float gsh[64];
    __shared__ float wsh2[2];
    if (tid < 64) gsh[tid] = 0.f;
    if (tid < 2) wsh2[tid] = 0.f;
    __syncthreads();

    float cv = (lane < 63) ? c[lane] : 0.f;
    float cn2 = waveReduceSum(cv * cv);
    float fcnl = cv * rsqrtf(cn2);

    int r0 = blockIdx.x * 16 + wid * 4;
    float gl = 0.f, lp = 0.f, ln = 0.f;
#pragma unroll
    for (int i = 0; i < 4; i++) {
        int r = r0 + i;
        if (r < 8000) {
            float val = (lane < 63) ? A[r * 63 + lane] : b[r];
            float s2 = waveReduceSum(val * val);
            float f = val * rsqrtf(s2);
            unsigned short h = f2bf(f);
            Fh[r * 64 + lane] = h;
            Fl[r * 64 + lane] = f2bf(f - bf2f(h));
            gl += f;
            float w = waveReduceSum(f * fcnl);
            if (lane == 0) {
                ws[WS_RNORM + r] = sqrtf(s2);
                lp += fmaxf(w, 0.f); ln += fmaxf(-w, 0.f);
            }
        } else {
            Fh[r * 64 + lane] = 0;
            Fl[r * 64 + lane] = 0;
        }
    }
    atomicAdd(&gsh[lane], gl);
    if (lane == 0) { atomicAdd(&wsh2[0], lp); atomicAdd(&wsh2[1], ln); }
    __syncthreads();
    if (tid < 64) ws[WS_GPART + blockIdx.x * 64 + tid] = gsh[tid];
    if (tid == 64) ws[WS_WPART + blockIdx.x * 2 + 0] = wsh2[0];
    if (tid == 65) ws[WS_WPART + blockIdx.x * 2 + 1] = wsh2[1];
}

// K2: plain-bf16 MFMA gram, register-resident B. (unchanged)
__global__ __launch_bounds__(256) void k_gram(
    const unsigned short* __restrict__ Fh, float* __restrict__ ws)
{
    int tid = threadIdx.x, lane = tid & 63, wid = tid >> 6;
    int m = lane & 15, quad = lane >> 4;
    int vbase = blockIdx.x * 256 + wid * 64;

    short8 AH[8];
#pragma unroll
    for (int pt = 0; pt < 4; pt++)
#pragma unroll
        for (int q = 0; q < 2; q++)
            AH[pt * 2 + q] = *(const short8*)(Fh + (vbase + pt * 16 + m) * 64 + q * 32 + quad * 8);

    float srr[16];
#pragma unroll
    for (int i = 0; i < 16; i++) srr[i] = 0.f;

    const int y = blockIdx.y;                 // u-tiles j = y + 32k, k=0..15
    const int boff = m * 64 + quad * 8;
    short8 B0[2], B1[2];
#pragma unroll
    for (int q = 0; q < 2; q++)
        B0[q] = *(const short8*)(Fh + y * 16 * 64 + boff + q * 32);

#pragma unroll 1
    for (int k2 = 0; k2 < 8; k2++) {
        int jB1 = y + 32 * (2 * k2 + 1);
#pragma unroll
        for (int q = 0; q < 2; q++)
            B1[q] = *(const short8*)(Fh + jB1 * 16 * 64 + boff + q * 32);
#pragma unroll
        for (int pt = 0; pt < 4; pt++) {
            f32x4 a = {0.f, 0.f, 0.f, 0.f};
            a = __builtin_amdgcn_mfma_f32_16x16x32_bf16(AH[pt * 2 + 0], B0[0], a, 0, 0, 0);
            a = __builtin_amdgcn_mfma_f32_16x16x32_bf16(AH[pt * 2 + 1], B0[1], a, 0, 0, 0);
#pragma unroll
            for (int r = 0; r < 4; r++) srr[pt * 4 + r] += fmaxf(a[r], 0.f);
        }
        if (k2 < 7) {
            int jB0 = y + 32 * (2 * k2 + 2);
#pragma unroll
            for (int q = 0; q < 2; q++)
                B0[q] = *(const short8*)(Fh + jB0 * 16 * 64 + boff + q * 32);
        }
#pragma unroll
        for (int pt = 0; pt < 4; pt++) {
            f32x4 a = {0.f, 0.f, 0.f, 0.f};
            a = __builtin_amdgcn_mfma_f32_16x16x32_bf16(AH[pt * 2 + 0], B1[0], a, 0, 0, 0);
            a = __builtin_amdgcn_mfma_f32_16x16x32_bf16(AH[pt * 2 + 1], B1[1], a, 0, 0, 0);
#pragma unroll
            for (int r = 0; r < 4; r++) srr[pt * 4 + r] += fmaxf(a[r], 0.f);
        }
    }
#pragma unroll
    for (int pt = 0; pt < 4; pt++)
#pragma unroll
        for (int r = 0; r < 4; r++) {
            float s = srr[pt * 4 + r];
            s += __shfl_xor(s, 1, 64); s += __shfl_xor(s, 2, 64);
            s += __shfl_xor(s, 4, 64); s += __shfl_xor(s, 8, 64);
            if (m == 0)
                ws[WS_SPART + y * 8192 + vbase + pt * 16 + quad * 4 + r] = s;
        }
}

// K3: fused mu0 + 4 sweeps + head, ONE cooperative kernel, 125x256.
// Cross-block data: agent-scope relaxed atomic STORES + batched sc0/sc1
// asm LOADS (32 in flight, one waitcnt). Barrier: arrival counter + release
// flag. mu state lives in LDS across sweeps.
__global__ __launch_bounds__(256) void k_mu_fused(
    const float* __restrict__ c,
    const float* __restrict__ th2cr, const float* __restrict__ th2rc,
    const float* __restrict__ th6r, const float* __restrict__ th6c,
    const float* __restrict__ th7, const float* __restrict__ W8,
    const float* __restrict__ b8, const int* __restrict__ zp,
    float* __restrict__ ws,
    const unsigned short* __restrict__ Fh, const unsigned short* __restrict__ Fl,
    const unsigned short* __restrict__ R2H, const unsigned short* __restrict__ R2L,
    float* __restrict__ out)
{
    __shared__ float XF[64][68];
    __shared__ unsigned short UHT[64][72], ULT[64][72];   // mu state, padded
    __shared__ float red[256], colp[256];
    __shared__ __align__(16) float wS[64], alS[64], beS[64], gaS[64], deS[64];
    __shared__ float fcnS[64], gS[64], sprow[64];
    __shared__ __align__(16) float e4sh[256];
    __shared__ float Ssh[64], ysh[64], feat[128], muzS[64];

    int tid = threadIdx.x, lane = tid & 63, wid = tid >> 6;
    int m = lane & 15, quad = lane >> 4;
    int v0 = blockIdx.x * 64;
    int cw = wid * 16 + m;
    int v = v0 + cw;
    int z = zp[0];
    int* cnt = (int*)(ws + WS_CNT);       // [0..7] arrivals, [8..15] release

    // persistent A-fragments (th2rr hi/lo) — loaded ONCE for all 5 sweeps
    short8 RH[8], RL[8];
#pragma unroll
    for (int pt = 0; pt < 4; pt++)
#pragma unroll
        for (int q = 0; q < 2; q++) {
            int off = (pt * 16 + m) * 64 + q * 32 + quad * 8;
            RH[pt * 2 + q] = *(const short8*)(R2H + off);
            RL[pt * 2 + q] = *(const short8*)(R2L + off);
        }

    // ---------------- phase 0: e4 + mu0 prep ----------------
    if (wid == 0) {
        float cv = (lane < 63) ? c[lane] : 0.f;
        float cn2 = waveReduceSum(cv * cv);
        fcnS[lane] = cv * rsqrtf(cn2);
        wS[lane] = ws[WS_W + lane];
    } else if (wid == 1) {
        alS[lane] = ws[WS_AL + lane]; beS[lane] = ws[WS_BE + lane];
        float wp = 0.f;
#pragma unroll
        for (int k = 0; k < 8; k++) wp += ws[WS_WPART + (lane + 64 * k) * 2];
        wp = waveReduceSum(wp);
        if (lane == 0) ws[WS_WSUM] = wp;       // same value from every block
    } else if (wid == 2) {
        gaS[lane] = ws[WS_GA + lane]; deS[lane] = ws[WS_DE + lane];
        float wn = 0.f;
#pragma unroll
        for (int k = 0; k < 8; k++) wn += ws[WS_WPART + (lane + 64 * k) * 2 + 1];
        wn = waveReduceSum(wn);
        if (lane == 0) ws[WS_WSUM + 1] = wn;
    }
    float gv = 0.f;
#pragma unroll 8
    for (int bb = 0; bb < 128; bb++) gv += ws[WS_GPART + (wid * 128 + bb) * 64 + lane];
    red[tid] = gv;
    __syncthreads();
    if (tid < 64) gS[tid] = red[tid] + red[64 + tid] + red[128 + tid] + red[192 + tid];
    __syncthreads();
    float sv = 0.f;
#pragma unroll
    for (int y = wid * 8; y < wid * 8 + 8; y++) sv += ws[WS_SPART + y * 8192 + v0 + lane];
    red[tid] = sv;
    __syncthreads();
    if (tid < 64) sprow[tid] = red[tid] + red[64 + tid] + red[128 + tid] + red[192 + tid];
    __syncthreads();

    for (int i2 = 0; i2 < 16; i2++) {
        int i = wid * 16 + i2;
        int vr = v0 + i;
        float fr = bf2f(Fh[vr * 64 + lane]) + bf2f(Fl[vr * 64 + lane]);
        float dw = waveReduceSum(fr * fcnS[lane]);
        float dg = waveReduceSum(fr * gS[lane]);
        if (lane == 0) {
            float spv = sprow[i];
            float4 ee;
            ee.x = spv - 1.0f;         // remove diagonal relu(1)
            ee.y = spv - dg;           // relu(-x) = relu(x) - x
            ee.z = fmaxf(dw, 0.f);
            ee.w = fmaxf(-dw, 0.f);
            *(float4*)(&e4sh[i * 4]) = ee;
        }
        XF[i][lane] = fr * ws[WS_RNORM + vr];   // mu0 row (fp32)
    }
    __syncthreads();

    short8 BH[2], BL[2];
#pragma unroll
    for (int q = 0; q < 2; q++) {
        float4 f0 = *(const float4*)(&XF[cw][q * 32 + quad * 8]);
        float4 f1 = *(const float4*)(&XF[cw][q * 32 + quad * 8 + 4]);
        float xv[8] = {f0.x, f0.y, f0.z, f0.w, f1.x, f1.y, f1.z, f1.w};
        short8 H, L;
#pragma unroll
        for (int j = 0; j < 8; j++) {
            unsigned short h = f2bf(xv[j]);
            H[j] = (short)h;
            L[j] = (short)f2bf(xv[j] - bf2f(h));
        }
        BH[q] = H; BL[q] = L;
    }
    float4 e = *(const float4*)(&e4sh[cw * 4]);   // persistent for all sweeps

    // ---------------- sweeps 0..4 ----------------
    for (int t = 0; t < 5; t++) {
        if (t > 0) {
            // Ssh = reduce CPART(t-1): batched coherent loads, fixed order
            red[tid] = sum32_coherent(ws + WS_CPART + (t - 1) * 8192 + wid * 64 + lane);
            __syncthreads();
            if (tid < 64) Ssh[tid] = red[tid] + red[64 + tid] + red[128 + tid] + red[192 + tid];
            __syncthreads();
            {
                int p = wid * 16 + m;
                float acc = 0.f;
                const float4* rowp = (const float4*)(th2cr + p * 64 + quad * 16);
#pragma unroll
                for (int kk = 0; kk < 4; kk++) {
                    float4 r4 = rowp[kk];
                    acc += r4.x * Ssh[quad * 16 + 4 * kk]     + r4.y * Ssh[quad * 16 + 4 * kk + 1]
                         + r4.z * Ssh[quad * 16 + 4 * kk + 2] + r4.w * Ssh[quad * 16 + 4 * kk + 3];
                }
                acc += __shfl_xor(acc, 16, 64);
                acc += __shfl_xor(acc, 32, 64);
                if (quad == 0)
                    ysh[p] = fmaxf(acc + ws[WS_T1C + p] + ws[WS_WSUM] * ws[WS_ECP + p]
                                   + ws[WS_WSUM + 1] * ws[WS_ECN + p], 0.f);
            }
            __syncthreads();
            {
                int p = wid * 16 + m;
                float acc = 0.f;
                const float4* rowp = (const float4*)(th2rc + p * 64 + quad * 16);
#pragma unroll
                for (int kk = 0; kk < 4; kk++) {
                    float4 r4 = rowp[kk];
                    acc += r4.x * ysh[quad * 16 + 4 * kk]     + r4.y * ysh[quad * 16 + 4 * kk + 1]
                         + r4.z * ysh[quad * 16 + 4 * kk + 2] + r4.w * ysh[quad * 16 + 4 * kk + 3];
                }
                acc += __shfl_xor(acc, 16, 64);
                acc += __shfl_xor(acc, 32, 64);
                if (quad == 0) wS[p] = acc + ws[WS_T1R + p];
            }
            // mu(t-1) fragments from LDS state
#pragma unroll
            for (int q = 0; q < 2; q++) {
                BH[q] = *(const short8*)(&UHT[cw][q * 32 + quad * 8]);
                BL[q] = *(const short8*)(&ULT[cw][q * 32 + quad * 8]);
            }
        }
        __syncthreads();   // wS ready; UHT reads done before overwrite

#pragma unroll
        for (int pt = 0; pt < 4; pt++) {
            f32x4 a = {0.f, 0.f, 0.f, 0.f};
#pragma unroll
            for (int q = 0; q < 2; q++) {
                a = __builtin_amdgcn_mfma_f32_16x16x32_bf16(RH[pt*2+q], BH[q], a, 0, 0, 0);
                a = __builtin_amdgcn_mfma_f32_16x16x32_bf16(RH[pt*2+q], BL[q], a, 0, 0, 0);
                a = __builtin_amdgcn_mfma_f32_16x16x32_bf16(RL[pt*2+q], BH[q], a, 0, 0, 0);
            }
            int pbase = pt * 16 + quad * 4;
            float4 w4 = *(const float4*)(wS + pbase);
            float4 a4 = *(const float4*)(alS + pbase);
            float4 b4 = *(const float4*)(beS + pbase);
            float4 g4 = *(const float4*)(gaS + pbase);
            float4 d4 = *(const float4*)(deS + pbase);
            float u0 = fmaxf(a[0] + w4.x + a4.x*e.x + b4.x*e.y + g4.x*e.z + d4.x*e.w, 0.f);
            float u1 = fmaxf(a[1] + w4.y + a4.y*e.x + b4.y*e.y + g4.y*e.z + d4.y*e.w, 0.f);
            float u2 = fmaxf(a[2] + w4.z + a4.z*e.x + b4.z*e.y + g4.z*e.z + d4.z*e.w, 0.f);
            float u3 = fmaxf(a[3] + w4.w + a4.w*e.x + b4.w*e.y + g4.w*e.z + d4.w*e.w, 0.f);
            if (t < 4) {
                ushort4 h4, l4;
                h4.x = f2bf(u0); l4.x = f2bf(u0 - bf2f(h4.x));
                h4.y = f2bf(u1); l4.y = f2bf(u1 - bf2f(h4.y));
                h4.z = f2bf(u2); l4.z = f2bf(u2 - bf2f(h4.z));
                h4.w = f2bf(u3); l4.w = f2bf(u3 - bf2f(h4.w));
                *(ushort4*)(&UHT[cw][pbase]) = h4;
                *(ushort4*)(&ULT[cw][pbase]) = l4;
            } else if (v == z) {
                __hip_atomic_store(&ws[WS_MUZ + pbase + 0], u0, __ATOMIC_RELAXED, __HIP_MEMORY_SCOPE_AGENT);
                __hip_atomic_store(&ws[WS_MUZ + pbase + 1], u1, __ATOMIC_RELAXED, __HIP_MEMORY_SCOPE_AGENT);
                __hip_atomic_store(&ws[WS_MUZ + pbase + 2], u2, __ATOMIC_RELAXED, __HIP_MEMORY_SCOPE_AGENT);
                __hip_atomic_store(&ws[WS_MUZ + pbase + 3], u3, __ATOMIC_RELAXED, __HIP_MEMORY_SCOPE_AGENT);
            }
            float c0 = u0, c1 = u1, c2 = u2, c3 = u3;
#pragma unroll
            for (int mm = 1; mm < 16; mm <<= 1) {
                c0 += __shfl_xor(c0, mm, 64);
                c1 += __shfl_xor(c1, mm, 64);
                c2 += __shfl_xor(c2, mm, 64);
                c3 += __shfl_xor(c3, mm, 64);
            }
            if (m == 0) {
                colp[wid * 64 + pbase + 0] = c0;
                colp[wid * 64 + pbase + 1] = c1;
                colp[wid * 64 + pbase + 2] = c2;
                colp[wid * 64 + pbase + 3] = c3;
            }
        }
        __syncthreads();
        if (tid < 64)
            __hip_atomic_store(&ws[WS_CPART + t * 8192 + blockIdx.x * 64 + tid],
                               colp[tid] + colp[64 + tid] + colp[128 + tid] + colp[192 + tid],
                               __ATOMIC_RELAXED, __HIP_MEMORY_SCOPE_AGENT);

        // ---- barrier: syncthreads drains the data stores (vmcnt(0) before
        // s_barrier), then arrival fetch_add + release-flag poll.
        __syncthreads();
        if (tid == 0) {
            int old = __hip_atomic_fetch_add(&cnt[t], 1, __ATOMIC_RELAXED, __HIP_MEMORY_SCOPE_AGENT);
            if (old == NBLK - 1) {
                __hip_atomic_store(&cnt[8 + t], 1, __ATOMIC_RELAXED, __HIP_MEMORY_SCOPE_AGENT);
            } else {
                while (__hip_atomic_load(&cnt[8 + t], __ATOMIC_RELAXED, __HIP_MEMORY_SCOPE_AGENT) == 0)
                    __builtin_amdgcn_s_sleep(1);
            }
        }
        __syncthreads();
    }

    // ---------------- head (block 0 only) ----------------
    if (blockIdx.x != 0) return;

    red[tid] = sum32_coherent(ws + WS_CPART + 4 * 8192 + wid * 64 + lane);
    if (tid < 64) {       // stage mu[z] with ONE coherent vector load
        float mz;
        asm volatile("global_load_dword %0, %1, off sc0 sc1"
                     : "=v"(mz) : "v"(ws + WS_MUZ + tid));
        asm volatile("s_waitcnt vmcnt(0)" ::: "memory");
        __builtin_amdgcn_sched_barrier(0);
        muzS[tid] = mz;
    }
    __syncthreads();
    if (tid < 64) Ssh[tid] = red[tid] + red[64 + tid] + red[128 + tid] + red[192 + tid];
    __syncthreads();
    int p = tid;
    if (p < 64) {
        float acc = ws[WS_T1C + p] + ws[WS_WSUM] * ws[WS_ECP + p]
                  + ws[WS_WSUM + 1] * ws[WS_ECN + p];
#pragma unroll 8
        for (int k = 0; k < 64; k++) acc += th2cr[p * 64 + k] * Ssh[k];
        ysh[p] = fmaxf(acc, 0.f);
    }
    __syncthreads();
    if (p < 64) {
        float t6 = 0.f, t7 = 0.f;
#pragma unroll 8
        for (int k = 0; k < 64; k++) {
            t6 += th6r[p * 64 + k] * Ssh[k] + th6c[p * 64 + k] * ysh[k];
            t7 += th7[p * 64 + k] * muzS[k];
        }
        feat[p] = 1.f / (1.f + expf(-t6));
        feat[64 + p] = 1.f / (1.f + expf(-t7));
    }
    __syncthreads();
    if (p < 2) {
        float o = b8[p];
        for (int i = 0; i < 128; i++) o += W8[p * 128 + i] * feat[i];
        out[p] = o;
    }
}

extern "C" void kernel_launch(void* const* d_in, const int* in_sizes, int n_in,
                              void* d_out, int out_size, void* d_ws, size_t ws_size,
                              hipStream_t stream) {
    (void)in_sizes; (void)n_in; (void)out_size; (void)ws_size;
    const float* A     = (const float*)d_in[0];
    const float* b     = (const float*)d_in[1];
    const float* c     = (const float*)d_in[2];
    const float* th1r  = (const float*)d_in[3];
    const float* th1c  = (const float*)d_in[4];
    const float* th2rr = (const float*)d_in[5];
    const float* th2rc = (const float*)d_in[6];
    const float* th2cr = (const float*)d_in[7];
    const float* th3rr = (const float*)d_in[8];
    const float* th3rc = (const float*)d_in[9];
    const float* th3cr = (const float*)d_in[10];
    const float* th4rr = (const float*)d_in[11];
    const float* th4rc = (const float*)d_in[12];
    const float* th4cr = (const float*)d_in[13];
    const float* th6r  = (const float*)d_in[14];
    const float* th6c  = (const float*)d_in[15];
    const float* th7   = (const float*)d_in[16];
    const float* W8    = (const float*)d_in[17];
    const float* b8    = (const float*)d_in[18];
    const int*   zp    = (const int*)d_in[19];
    float* ws  = (float*)d_ws;
    float* out = (float*)d_out;
    unsigned short* Fh  = (unsigned short*)(ws + WS_FH);
    unsigned short* Fl  = (unsigned short*)(ws + WS_FL);
    unsigned short* R2H = (unsigned short*)(ws + WS_R2H);
    unsigned short* R2L = (unsigned short*)(ws + WS_R2L);

    k_fr<<<513, 256, 0, stream>>>(A, b, c, th1r, th1c, th2rr, th2rc, th3rr, th3rc,
                                  th3cr, th4rr, th4rc, th4cr, zp, Fh, Fl, R2H, R2L, ws);
    k_gram<<<dim3(32, 32), 256, 0, stream>>>(Fh, ws);
    {
        const unsigned short* Fhc = Fh;
        const unsigned short* Flc = Fl;
        const unsigned short* R2Hc = R2H;
        const unsigned short* R2Lc = R2L;
        void* kargs[] = {
            (void*)&c, (void*)&th2cr, (void*)&th2rc, (void*)&th6r, (void*)&th6c,
            (void*)&th7, (void*)&W8, (void*)&b8, (void*)&zp, (void*)&ws,
            (void*)&Fhc, (void*)&Flc, (void*)&R2Hc, (void*)&R2Lc, (void*)&out };
        hipLaunchCooperativeKernel((const void*)k_mu_fused, dim3(NBLK), dim3(256),
                                   kargs, 0, stream);
    }
}

// Round 4
// 227.407 us; speedup vs baseline: 1.7950x; 1.0330x over previous
//
#include <hip/hip_runtime.h>
#include <math.h>

typedef __attribute__((ext_vector_type(8))) short short8;
typedef __attribute__((ext_vector_type(4))) float f32x4;

// ---- workspace layout (float offsets) ---- total 905216 floats = 3.62 MB
#define WS_SPART 0          // srr partials [32][8192]           -> 262144
#define WS_GPART 262144     // g partials [512][64]              -> 294912
#define WS_WPART 294912     // wsum partials [512][2]            -> 295936
#define WS_CPART 295936     // colsum partials [5][128*64] (PADDED) -> 336896
#define WS_T1R   336896
#define WS_T1C   336960
#define WS_AL    337024
#define WS_BE    337088
#define WS_GA    337152
#define WS_DE    337216
#define WS_ECP   337280
#define WS_ECN   337344
#define WS_W     337408     // w for sweep 0 only
#define WS_MUZ   337472
#define WS_WSUM  337536     // reduced wsum_pos/neg (pad 64)
#define WS_RNORM 337600     // row norms [8192]                  -> 345792
#define WS_R2H   345792     // th2rr bf16 hi ushort[4096]        -> 347840
#define WS_R2L   347840     //                                   -> 349888
#define WS_FLAG  349888     // sweep flags int[5][128] (pad 125..127 preset 1)
#define WS_FH    380928     // bf16 hi ushort[8192*64]
#define WS_FL    643072     //                                   -> 905216

#define NBLK 125

__device__ __forceinline__ float waveReduceSum(float v) {
#pragma unroll
    for (int m = 32; m >= 1; m >>= 1) v += __shfl_xor(v, m, 64);
    return v;
}
__device__ __forceinline__ unsigned short f2bf(float f) {
    unsigned int u = __float_as_uint(f);
    unsigned int r = (u + 0x7fffu + ((u >> 16) & 1u)) >> 16;
    return (unsigned short)r;
}
__device__ __forceinline__ float bf2f(unsigned short h) {
    return __uint_as_float(((unsigned int)h) << 16);
}

// Batched coherent (cache-bypass) strided sum: 32 loads in flight, ONE wait.
// Sum order = ascending i (bit-exact vs the serial loop).
__device__ __forceinline__ float sum32_coherent(const float* base) {
    float v[32];
#pragma unroll
    for (int i = 0; i < 32; i++)
        asm volatile("global_load_dword %0, %1, off sc0 sc1"
                     : "=v"(v[i]) : "v"(base + i * 256));
    asm volatile("s_waitcnt vmcnt(0)" ::: "memory");
    __builtin_amdgcn_sched_barrier(0);
    float s = 0.f;
#pragma unroll
    for (int i = 0; i < 32; i++) s += v[i];
    return s;
}

// Wave-0 poll of 128 per-block flags (125 real + 3 preset-1 pad), coherent.
__device__ __forceinline__ void pollFlags(const int* fb, int lane) {
    for (;;) {
        int f0, f1;
        asm volatile("global_load_dword %0, %1, off sc0 sc1"
                     : "=v"(f0) : "v"(fb + lane));
        asm volatile("global_load_dword %0, %1, off sc0 sc1"
                     : "=v"(f1) : "v"(fb + 64 + lane));
        asm volatile("s_waitcnt vmcnt(0)" : "+v"(f0), "+v"(f1) :: "memory");
        __builtin_amdgcn_sched_barrier(0);
        if (__all((f0 == 1) && (f1 == 1))) return;
        __builtin_amdgcn_s_sleep(1);
    }
}

// K1: blocks 0..511: 16 rows each -> Fh/Fl + rnorm + g/wsum partials.
//     block 512: setup math + th2rr bf16 split + flag/pad init.
__global__ __launch_bounds__(256) void k_fr(
    const float* __restrict__ A, const float* __restrict__ b, const float* __restrict__ c,
    const float* __restrict__ th1r, const float* __restrict__ th1c,
    const float* __restrict__ th2rr, const float* __restrict__ th2rc,
    const float* __restrict__ th3rr, const float* __restrict__ th3rc, const float* __restrict__ th3cr,
    const float* __restrict__ th4rr, const float* __restrict__ th4rc, const float* __restrict__ th4cr,
    const int* __restrict__ zp,
    unsigned short* __restrict__ Fh, unsigned short* __restrict__ Fl,
    unsigned short* __restrict__ R2H, unsigned short* __restrict__ R2L,
    float* __restrict__ ws)
{
    int tid = threadIdx.x, lane = tid & 63, wid = tid >> 6;

    if (blockIdx.x == 512) {
        __shared__ float fcraw[64], fz[64], sh4a[64], sh4b[64];
        int p = lane;
        int z = zp[0];
        float cv = (p < 63) ? c[p] : 0.f;
        fcraw[p] = cv;
        float av = (p < 63) ? A[z * 63 + p] : b[z];
        float s2 = waveReduceSum(av * av);
        fz[p] = av * rsqrtf(s2);
        __syncthreads();

        float t1 = 0.f, t2 = 0.f, w0 = 0.f;
#pragma unroll 8
        for (int k = 0; k < 64; k++) {
            t1 += th1r[p * 64 + k] * fz[k];
            t2 += th1c[p * 64 + k] * fz[k];
            w0 += th2rc[p * 64 + k] * fcraw[k];
        }
        ws[WS_T1R + p] = t1;
        ws[WS_T1C + p] = t2;
        ws[WS_W + p] = t1 + w0;               // w for sweep 0

        sh4a[p] = th4rr[p];
        sh4b[p] = th4rc[p];
        __syncthreads();
        float a = 0.f, bb = 0.f, g = 0.f, d = 0.f;
#pragma unroll 8
        for (int k = 0; k < 64; k++) {
            float t4 = sh4a[k];
            a  += th3rr[p * 64 + k] * fmaxf(t4, 0.f);
            bb += th3rr[p * 64 + k] * fmaxf(-t4, 0.f);
            float t5 = sh4b[k];
            g  += th3rc[p * 64 + k] * fmaxf(t5, 0.f);
            d  += th3rc[p * 64 + k] * fmaxf(-t5, 0.f);
        }
        ws[WS_AL + p] = a; ws[WS_BE + p] = bb;
        ws[WS_GA + p] = g; ws[WS_DE + p] = d;
        __syncthreads();
        sh4a[p] = th4cr[p];
        __syncthreads();
        float e1 = 0.f, e2 = 0.f;
#pragma unroll 8
        for (int k = 0; k < 64; k++) {
            float t6 = sh4a[k];
            e1 += th3cr[p * 64 + k] * fmaxf(t6, 0.f);
            e2 += th3cr[p * 64 + k] * fmaxf(-t6, 0.f);
        }
        ws[WS_ECP + p] = e1; ws[WS_ECN + p] = e2;

        // flags: [5][128]; real blocks 0..124 start 0, pad 125..127 preset 1
        if (tid < 128) {
            int* fl = (int*)(ws + WS_FLAG);
#pragma unroll
            for (int t5 = 0; t5 < 5; t5++)
                fl[t5 * 128 + tid] = (tid >= NBLK) ? 1 : 0;
        }
        // zero CPART pad rows (blk 125..127) for all 5 sweeps (+0.0f bit-exact)
        if (tid < 192) {
#pragma unroll
            for (int t5 = 0; t5 < 5; t5++)
                ws[WS_CPART + t5 * 8192 + 8000 + tid] = 0.f;
        }

#pragma unroll
        for (int i = 0; i < 16; i++) {
            int idx = tid * 16 + i;
            float f = th2rr[idx];
            unsigned short h = f2bf(f);
            R2H[idx] = h;
            R2L[idx] = f2bf(f - bf2f(h));
        }
        return;
    }

    __shared__ float gsh[64];
    __shared__ float wsh2[2];
    if (tid < 64) gsh[tid] = 0.f;
    if (tid < 2) wsh2[tid] = 0.f;
    __syncthreads();

    float cv = (lane < 63) ? c[lane] : 0.f;
    float cn2 = waveReduceSum(cv * cv);
    float fcnl = cv * rsqrtf(cn2);

    int r0 = blockIdx.x * 16 + wid * 4;
    float gl = 0.f, lp = 0.f, ln = 0.f;
#pragma unroll
    for (int i = 0; i < 4; i++) {
        int r = r0 + i;
        if (r < 8000) {
            float val = (lane < 63) ? A[r * 63 + lane] : b[r];
            float s2 = waveReduceSum(val * val);
            float f = val * rsqrtf(s2);
            unsigned short h = f2bf(f);
            Fh[r * 64 + lane] = h;
            Fl[r * 64 + lane] = f2bf(f - bf2f(h));
            gl += f;
            float w = waveReduceSum(f * fcnl);
            if (lane == 0) {
                ws[WS_RNORM + r] = sqrtf(s2);
                lp += fmaxf(w, 0.f); ln += fmaxf(-w, 0.f);
            }
        } else {
            Fh[r * 64 + lane] = 0;
            Fl[r * 64 + lane] = 0;
        }
    }
    atomicAdd(&gsh[lane], gl);
    if (lane == 0) { atomicAdd(&wsh2[0], lp); atomicAdd(&wsh2[1], ln); }
    __syncthreads();
    if (tid < 64) ws[WS_GPART + blockIdx.x * 64 + tid] = gsh[tid];
    if (tid == 64) ws[WS_WPART + blockIdx.x * 2 + 0] = wsh2[0];
    if (tid == 65) ws[WS_WPART + blockIdx.x * 2 + 1] = wsh2[1];
}

// K2: plain-bf16 MFMA gram, register-resident B. (unchanged)
__global__ __launch_bounds__(256) void k_gram(
    const unsigned short* __restrict__ Fh, float* __restrict__ ws)
{
    int tid = threadIdx.x, lane = tid & 63, wid = tid >> 6;
    int m = lane & 15, quad = lane >> 4;
    int vbase = blockIdx.x * 256 + wid * 64;

    short8 AH[8];
#pragma unroll
    for (int pt = 0; pt < 4; pt++)
#pragma unroll
        for (int q = 0; q < 2; q++)
            AH[pt * 2 + q] = *(const short8*)(Fh + (vbase + pt * 16 + m) * 64 + q * 32 + quad * 8);

    float srr[16];
#pragma unroll
    for (int i = 0; i < 16; i++) srr[i] = 0.f;

    const int y = blockIdx.y;                 // u-tiles j = y + 32k, k=0..15
    const int boff = m * 64 + quad * 8;
    short8 B0[2], B1[2];
#pragma unroll
    for (int q = 0; q < 2; q++)
        B0[q] = *(const short8*)(Fh + y * 16 * 64 + boff + q * 32);

#pragma unroll 1
    for (int k2 = 0; k2 < 8; k2++) {
        int jB1 = y + 32 * (2 * k2 + 1);
#pragma unroll
        for (int q = 0; q < 2; q++)
            B1[q] = *(const short8*)(Fh + jB1 * 16 * 64 + boff + q * 32);
#pragma unroll
        for (int pt = 0; pt < 4; pt++) {
            f32x4 a = {0.f, 0.f, 0.f, 0.f};
            a = __builtin_amdgcn_mfma_f32_16x16x32_bf16(AH[pt * 2 + 0], B0[0], a, 0, 0, 0);
            a = __builtin_amdgcn_mfma_f32_16x16x32_bf16(AH[pt * 2 + 1], B0[1], a, 0, 0, 0);
#pragma unroll
            for (int r = 0; r < 4; r++) srr[pt * 4 + r] += fmaxf(a[r], 0.f);
        }
        if (k2 < 7) {
            int jB0 = y + 32 * (2 * k2 + 2);
#pragma unroll
            for (int q = 0; q < 2; q++)
                B0[q] = *(const short8*)(Fh + jB0 * 16 * 64 + boff + q * 32);
        }
#pragma unroll
        for (int pt = 0; pt < 4; pt++) {
            f32x4 a = {0.f, 0.f, 0.f, 0.f};
            a = __builtin_amdgcn_mfma_f32_16x16x32_bf16(AH[pt * 2 + 0], B1[0], a, 0, 0, 0);
            a = __builtin_amdgcn_mfma_f32_16x16x32_bf16(AH[pt * 2 + 1], B1[1], a, 0, 0, 0);
#pragma unroll
            for (int r = 0; r < 4; r++) srr[pt * 4 + r] += fmaxf(a[r], 0.f);
        }
    }
#pragma unroll
    for (int pt = 0; pt < 4; pt++)
#pragma unroll
        for (int r = 0; r < 4; r++) {
            float s = srr[pt * 4 + r];
            s += __shfl_xor(s, 1, 64); s += __shfl_xor(s, 2, 64);
            s += __shfl_xor(s, 4, 64); s += __shfl_xor(s, 8, 64);
            if (m == 0)
                ws[WS_SPART + y * 8192 + vbase + pt * 16 + quad * 4 + r] = s;
        }
}

// K3: fused mu0 + 4 sweeps + head, ONE cooperative kernel, 125x256.
// Sync: per-sweep flag array (no RMW, no release). Each block stores its
// CPART rows (agent atomics), syncthreads (per-wave vmcnt0 drain), stores
// its flag, and SELF-POLLS all flags with batched sc0/sc1 loads. MFMA for
// sweep t runs BEFORE the poll (no cross-block dep) to hide flag latency.
__global__ __launch_bounds__(256) void k_mu_fused(
    const float* __restrict__ c,
    const float* __restrict__ th2cr, const float* __restrict__ th2rc,
    const float* __restrict__ th6r, const float* __restrict__ th6c,
    const float* __restrict__ th7, const float* __restrict__ W8,
    const float* __restrict__ b8, const int* __restrict__ zp,
    float* __restrict__ ws,
    const unsigned short* __restrict__ Fh, const unsigned short* __restrict__ Fl,
    const unsigned short* __restrict__ R2H, const unsigned short* __restrict__ R2L,
    float* __restrict__ out)
{
    __shared__ float XF[64][68];
    __shared__ unsigned short UHT[64][72], ULT[64][72];   // mu state, padded
    __shared__ float red[256], colp[256];
    __shared__ __align__(16) float wS[64], alS[64], beS[64], gaS[64], deS[64];
    __shared__ float fcnS[64], gS[64], sprow[64];
    __shared__ __align__(16) float e4sh[256];
    __shared__ float Ssh[64], ysh[64], feat[128], muzS[64];

    int tid = threadIdx.x, lane = tid & 63, wid = tid >> 6;
    int m = lane & 15, quad = lane >> 4;
    int v0 = blockIdx.x * 64;
    int cw = wid * 16 + m;
    int v = v0 + cw;
    int z = zp[0];
    int* flags = (int*)(ws + WS_FLAG);

    // persistent A-fragments (th2rr hi/lo) — loaded ONCE for all 5 sweeps
    short8 RH[8], RL[8];
#pragma unroll
    for (int pt = 0; pt < 4; pt++)
#pragma unroll
        for (int q = 0; q < 2; q++) {
            int off = (pt * 16 + m) * 64 + q * 32 + quad * 8;
            RH[pt * 2 + q] = *(const short8*)(R2H + off);
            RL[pt * 2 + q] = *(const short8*)(R2L + off);
        }

    // ---------------- phase 0: e4 + mu0 prep ----------------
    if (wid == 0) {
        float cv = (lane < 63) ? c[lane] : 0.f;
        float cn2 = waveReduceSum(cv * cv);
        fcnS[lane] = cv * rsqrtf(cn2);
        wS[lane] = ws[WS_W + lane];
    } else if (wid == 1) {
        alS[lane] = ws[WS_AL + lane]; beS[lane] = ws[WS_BE + lane];
        float wp = 0.f;
#pragma unroll
        for (int k = 0; k < 8; k++) wp += ws[WS_WPART + (lane + 64 * k) * 2];
        wp = waveReduceSum(wp);
        if (lane == 0) ws[WS_WSUM] = wp;       // same value from every block
    } else if (wid == 2) {
        gaS[lane] = ws[WS_GA + lane]; deS[lane] = ws[WS_DE + lane];
        float wn = 0.f;
#pragma unroll
        for (int k = 0; k < 8; k++) wn += ws[WS_WPART + (lane + 64 * k) * 2 + 1];
        wn = waveReduceSum(wn);
        if (lane == 0) ws[WS_WSUM + 1] = wn;
    }
    float gv = 0.f;
#pragma unroll 32
    for (int bb = 0; bb < 128; bb++) gv += ws[WS_GPART + (wid * 128 + bb) * 64 + lane];
    red[tid] = gv;
    __syncthreads();
    if (tid < 64) gS[tid] = red[tid] + red[64 + tid] + red[128 + tid] + red[192 + tid];
    __syncthreads();
    float sv = 0.f;
#pragma unroll
    for (int y = wid * 8; y < wid * 8 + 8; y++) sv += ws[WS_SPART + y * 8192 + v0 + lane];
    red[tid] = sv;
    __syncthreads();
    if (tid < 64) sprow[tid] = red[tid] + red[64 + tid] + red[128 + tid] + red[192 + tid];
    __syncthreads();

    for (int i2 = 0; i2 < 16; i2++) {
        int i = wid * 16 + i2;
        int vr = v0 + i;
        float fr = bf2f(Fh[vr * 64 + lane]) + bf2f(Fl[vr * 64 + lane]);
        float dw = waveReduceSum(fr * fcnS[lane]);
        float dg = waveReduceSum(fr * gS[lane]);
        if (lane == 0) {
            float spv = sprow[i];
            float4 ee;
            ee.x = spv - 1.0f;         // remove diagonal relu(1)
            ee.y = spv - dg;           // relu(-x) = relu(x) - x
            ee.z = fmaxf(dw, 0.f);
            ee.w = fmaxf(-dw, 0.f);
            *(float4*)(&e4sh[i * 4]) = ee;
        }
        XF[i][lane] = fr * ws[WS_RNORM + vr];   // mu0 row (fp32)
    }
    __syncthreads();

    short8 BH[2], BL[2];
#pragma unroll
    for (int q = 0; q < 2; q++) {
        float4 f0 = *(const float4*)(&XF[cw][q * 32 + quad * 8]);
        float4 f1 = *(const float4*)(&XF[cw][q * 32 + quad * 8 + 4]);
        float xv[8] = {f0.x, f0.y, f0.z, f0.w, f1.x, f1.y, f1.z, f1.w};
        short8 H, L;
#pragma unroll
        for (int j = 0; j < 8; j++) {
            unsigned short h = f2bf(xv[j]);
            H[j] = (short)h;
            L[j] = (short)f2bf(xv[j] - bf2f(h));
        }
        BH[q] = H; BL[q] = L;
    }
    float4 e = *(const float4*)(&e4sh[cw * 4]);   // persistent for all sweeps

    // ---------------- sweeps 0..4 ----------------
    for (int t = 0; t < 5; t++) {
        if (t > 0) {
            // mu(t-1) fragments from LDS (written last sweep, synced)
#pragma unroll
            for (int q = 0; q < 2; q++) {
                BH[q] = *(const short8*)(&UHT[cw][q * 32 + quad * 8]);
                BL[q] = *(const short8*)(&ULT[cw][q * 32 + quad * 8]);
            }
        }
        // ---- MFMA first: no cross-block dependency; hides flag latency
        f32x4 acc[4];
#pragma unroll
        for (int pt = 0; pt < 4; pt++) {
            f32x4 a = {0.f, 0.f, 0.f, 0.f};
#pragma unroll
            for (int q = 0; q < 2; q++) {
                a = __builtin_amdgcn_mfma_f32_16x16x32_bf16(RH[pt*2+q], BH[q], a, 0, 0, 0);
                a = __builtin_amdgcn_mfma_f32_16x16x32_bf16(RH[pt*2+q], BL[q], a, 0, 0, 0);
                a = __builtin_amdgcn_mfma_f32_16x16x32_bf16(RL[pt*2+q], BH[q], a, 0, 0, 0);
            }
            acc[pt] = a;
        }

        if (t > 0) {
            // ---- wait for CPART(t-1) producers (flags likely already set)
            if (wid == 0) pollFlags(flags + (t - 1) * 128, lane);
            __syncthreads();
            // Ssh = reduce CPART(t-1): batched coherent loads, fixed order
            red[tid] = sum32_coherent(ws + WS_CPART + (t - 1) * 8192 + wid * 64 + lane);
            __syncthreads();
            if (tid < 64) Ssh[tid] = red[tid] + red[64 + tid] + red[128 + tid] + red[192 + tid];
            __syncthreads();
            {
                int p = wid * 16 + m;
                float acc2 = 0.f;
                const float4* rowp = (const float4*)(th2cr + p * 64 + quad * 16);
#pragma unroll
                for (int kk = 0; kk < 4; kk++) {
                    float4 r4 = rowp[kk];
                    acc2 += r4.x * Ssh[quad * 16 + 4 * kk]     + r4.y * Ssh[quad * 16 + 4 * kk + 1]
                          + r4.z * Ssh[quad * 16 + 4 * kk + 2] + r4.w * Ssh[quad * 16 + 4 * kk + 3];
                }
                acc2 += __shfl_xor(acc2, 16, 64);
                acc2 += __shfl_xor(acc2, 32, 64);
                if (quad == 0)
                    ysh[p] = fmaxf(acc2 + ws[WS_T1C + p] + ws[WS_WSUM] * ws[WS_ECP + p]
                                   + ws[WS_WSUM + 1] * ws[WS_ECN + p], 0.f);
            }
            __syncthreads();
            {
                int p = wid * 16 + m;
                float acc2 = 0.f;
                const float4* rowp = (const float4*)(th2rc + p * 64 + quad * 16);
#pragma unroll
                for (int kk = 0; kk < 4; kk++) {
                    float4 r4 = rowp[kk];
                    acc2 += r4.x * ysh[quad * 16 + 4 * kk]     + r4.y * ysh[quad * 16 + 4 * kk + 1]
                          + r4.z * ysh[quad * 16 + 4 * kk + 2] + r4.w * ysh[quad * 16 + 4 * kk + 3];
                }
                acc2 += __shfl_xor(acc2, 16, 64);
                acc2 += __shfl_xor(acc2, 32, 64);
                if (quad == 0) wS[p] = acc2 + ws[WS_T1R + p];
            }
            __syncthreads();   // wS ready
        }

        // ---- epilogue
#pragma unroll
        for (int pt = 0; pt < 4; pt++) {
            f32x4 a = acc[pt];
            int pbase = pt * 16 + quad * 4;
            float4 w4 = *(const float4*)(wS + pbase);
            float4 a4 = *(const float4*)(alS + pbase);
            float4 b4 = *(const float4*)(beS + pbase);
            float4 g4 = *(const float4*)(gaS + pbase);
            float4 d4 = *(const float4*)(deS + pbase);
            float u0 = fmaxf(a[0] + w4.x + a4.x*e.x + b4.x*e.y + g4.x*e.z + d4.x*e.w, 0.f);
            float u1 = fmaxf(a[1] + w4.y + a4.y*e.x + b4.y*e.y + g4.y*e.z + d4.y*e.w, 0.f);
            float u2 = fmaxf(a[2] + w4.z + a4.z*e.x + b4.z*e.y + g4.z*e.z + d4.z*e.w, 0.f);
            float u3 = fmaxf(a[3] + w4.w + a4.w*e.x + b4.w*e.y + g4.w*e.z + d4.w*e.w, 0.f);
            if (t < 4) {
                ushort4 h4, l4;
                h4.x = f2bf(u0); l4.x = f2bf(u0 - bf2f(h4.x));
                h4.y = f2bf(u1); l4.y = f2bf(u1 - bf2f(h4.y));
                h4.z = f2bf(u2); l4.z = f2bf(u2 - bf2f(h4.z));
                h4.w = f2bf(u3); l4.w = f2bf(u3 - bf2f(h4.w));
                *(ushort4*)(&UHT[cw][pbase]) = h4;
                *(ushort4*)(&ULT[cw][pbase]) = l4;
            } else if (v == z) {
                __hip_atomic_store(&ws[WS_MUZ + pbase + 0], u0, __ATOMIC_RELAXED, __HIP_MEMORY_SCOPE_AGENT);
                __hip_atomic_store(&ws[WS_MUZ + pbase + 1], u1, __ATOMIC_RELAXED, __HIP_MEMORY_SCOPE_AGENT);
                __hip_atomic_store(&ws[WS_MUZ + pbase + 2], u2, __ATOMIC_RELAXED, __HIP_MEMORY_SCOPE_AGENT);
                __hip_atomic_store(&ws[WS_MUZ + pbase + 3], u3, __ATOMIC_RELAXED, __HIP_MEMORY_SCOPE_AGENT);
            }
            float c0 = u0, c1 = u1, c2 = u2, c3 = u3;
#pragma unroll
            for (int mm = 1; mm < 16; mm <<= 1) {
                c0 += __shfl_xor(c0, mm, 64);
                c1 += __shfl_xor(c1, mm, 64);
                c2 += __shfl_xor(c2, mm, 64);
                c3 += __shfl_xor(c3, mm, 64);
            }
            if (m == 0) {
                colp[wid * 64 + pbase + 0] = c0;
                colp[wid * 64 + pbase + 1] = c1;
                colp[wid * 64 + pbase + 2] = c2;
                colp[wid * 64 + pbase + 3] = c3;
            }
        }
        __syncthreads();
        if (tid < 64)
            __hip_atomic_store(&ws[WS_CPART + t * 8192 + blockIdx.x * 64 + tid],
                               colp[tid] + colp[64 + tid] + colp[128 + tid] + colp[192 + tid],
                               __ATOMIC_RELAXED, __HIP_MEMORY_SCOPE_AGENT);
        // per-wave vmcnt(0) drain before s_barrier ⇒ CPART at coherence point
        __syncthreads();
        if (tid == 0) {
            asm volatile("s_waitcnt vmcnt(0)" ::: "memory");  // belt & braces
            __hip_atomic_store(&flags[t * 128 + (int)blockIdx.x], 1,
                               __ATOMIC_RELAXED, __HIP_MEMORY_SCOPE_AGENT);
        }
    }

    // ---------------- head (block 0 only) ----------------
    if (blockIdx.x != 0) return;

    if (wid == 0) pollFlags(flags + 4 * 128, lane);
    __syncthreads();

    red[tid] = sum32_coherent(ws + WS_CPART + 4 * 8192 + wid * 64 + lane);
    if (tid < 64) {       // stage mu[z] with ONE coherent load per lane
        float mz;
        asm volatile("global_load_dword %0, %1, off sc0 sc1"
                     : "=v"(mz) : "v"(ws + WS_MUZ + tid));
        asm volatile("s_waitcnt vmcnt(0)" : "+v"(mz) :: "memory");
        __builtin_amdgcn_sched_barrier(0);
        muzS[tid] = mz;
    }
    __syncthreads();
    if (tid < 64) Ssh[tid] = red[tid] + red[64 + tid] + red[128 + tid] + red[192 + tid];
    __syncthreads();
    int p = tid;
    if (p < 64) {
        float acc2 = ws[WS_T1C + p] + ws[WS_WSUM] * ws[WS_ECP + p]
                   + ws[WS_WSUM + 1] * ws[WS_ECN + p];
#pragma unroll 8
        for (int k = 0; k < 64; k++) acc2 += th2cr[p * 64 + k] * Ssh[k];
        ysh[p] = fmaxf(acc2, 0.f);
    }
    __syncthreads();
    if (p < 64) {
        float t6 = 0.f, t7 = 0.f;
#pragma unroll 8
        for (int k = 0; k < 64; k++) {
            t6 += th6r[p * 64 + k] * Ssh[k] + th6c[p * 64 + k] * ysh[k];
            t7 += th7[p * 64 + k] * muzS[k];
        }
        feat[p] = 1.f / (1.f + expf(-t6));
        feat[64 + p] = 1.f / (1.f + expf(-t7));
    }
    __syncthreads();
    if (p < 2) {
        float o = b8[p];
        for (int i = 0; i < 128; i++) o += W8[p * 128 + i] * feat[i];
        out[p] = o;
    }
}

extern "C" void kernel_launch(void* const* d_in, const int* in_sizes, int n_in,
                              void* d_out, int out_size, void* d_ws, size_t ws_size,
                              hipStream_t stream) {
    (void)in_sizes; (void)n_in; (void)out_size; (void)ws_size;
    const float* A     = (const float*)d_in[0];
    const float* b     = (const float*)d_in[1];
    const float* c     = (const float*)d_in[2];
    const float* th1r  = (const float*)d_in[3];
    const float* th1c  = (const float*)d_in[4];
    const float* th2rr = (const float*)d_in[5];
    const float* th2rc = (const float*)d_in[6];
    const float* th2cr = (const float*)d_in[7];
    const float* th3rr = (const float*)d_in[8];
    const float* th3rc = (const float*)d_in[9];
    const float* th3cr = (const float*)d_in[10];
    const float* th4rr = (const float*)d_in[11];
    const float* th4rc = (const float*)d_in[12];
    const float* th4cr = (const float*)d_in[13];
    const float* th6r  = (const float*)d_in[14];
    const float* th6c  = (const float*)d_in[15];
    const float* th7   = (const float*)d_in[16];
    const float* W8    = (const float*)d_in[17];
    const float* b8    = (const float*)d_in[18];
    const int*   zp    = (const int*)d_in[19];
    float* ws  = (float*)d_ws;
    float* out = (float*)d_out;
    unsigned short* Fh  = (unsigned short*)(ws + WS_FH);
    unsigned short* Fl  = (unsigned short*)(ws + WS_FL);
    unsigned short* R2H = (unsigned short*)(ws + WS_R2H);
    unsigned short* R2L = (unsigned short*)(ws + WS_R2L);

    k_fr<<<513, 256, 0, stream>>>(A, b, c, th1r, th1c, th2rr, th2rc, th3rr, th3rc,
                                  th3cr, th4rr, th4rc, th4cr, zp, Fh, Fl, R2H, R2L, ws);
    k_gram<<<dim3(32, 32), 256, 0, stream>>>(Fh, ws);
    {
        const unsigned short* Fhc = Fh;
        const unsigned short* Flc = Fl;
        const unsigned short* R2Hc = R2H;
        const unsigned short* R2Lc = R2L;
        void* kargs[] = {
            (void*)&c, (void*)&th2cr, (void*)&th2rc, (void*)&th6r, (void*)&th6c,
            (void*)&th7, (void*)&W8, (void*)&b8, (void*)&zp, (void*)&ws,
            (void*)&Fhc, (void*)&Flc, (void*)&R2Hc, (void*)&R2Lc, (void*)&out };
        hipLaunchCooperativeKernel((const void*)k_mu_fused, dim3(NBLK), dim3(256),
                                   kargs, 0, stream);
    }
}

// Round 5
// 217.932 us; speedup vs baseline: 1.8730x; 1.0435x over previous
//
#include <hip/hip_runtime.h>
#include <math.h>

typedef __attribute__((ext_vector_type(8))) short short8;
typedef __attribute__((ext_vector_type(4))) float f32x4;

// ---- workspace layout (float offsets) ---- total 905216 floats = 3.62 MB
#define WS_SPART 0          // srr partials [32][8192]           -> 262144
#define WS_GPART 262144     // g partials [512][64]              -> 294912
#define WS_WPART 294912     // wsum partials [512][2]            -> 295936
#define WS_CPART 295936     // colsum partials [5][128*64] (PADDED) -> 336896
#define WS_T1R   336896
#define WS_T1C   336960
#define WS_AL    337024
#define WS_BE    337088
#define WS_GA    337152
#define WS_DE    337216
#define WS_ECP   337280
#define WS_ECN   337344
#define WS_W     337408     // w for sweep 0 only
#define WS_MUZ   337472
#define WS_WSUM  337536     // reduced wsum_pos/neg (pad 64)
#define WS_RNORM 337600     // row norms [8192]                  -> 345792
#define WS_R2H   345792     // th2rr bf16 hi ushort[4096]        -> 347840
#define WS_R2L   347840     //                                   -> 349888
#define WS_FLAG  349888     // sweep flags int[5][128] (pad 125..127 preset 1)
#define WS_GS    350528     // reduced g[64] (written by k_gram reducer block)
#define WS_FH    380928     // bf16 hi ushort[8192*64]
#define WS_FL    643072     //                                   -> 905216

#define NBLK 125

__device__ __forceinline__ float waveReduceSum(float v) {
#pragma unroll
    for (int m = 32; m >= 1; m >>= 1) v += __shfl_xor(v, m, 64);
    return v;
}
__device__ __forceinline__ unsigned short f2bf(float f) {
    unsigned int u = __float_as_uint(f);
    unsigned int r = (u + 0x7fffu + ((u >> 16) & 1u)) >> 16;
    return (unsigned short)r;
}
__device__ __forceinline__ float bf2f(unsigned short h) {
    return __uint_as_float(((unsigned int)h) << 16);
}

// Batched coherent (cache-bypass) strided sum: 32 loads in flight, ONE wait.
__device__ __forceinline__ float sum32_coherent(const float* base) {
    float v[32];
#pragma unroll
    for (int i = 0; i < 32; i++)
        asm volatile("global_load_dword %0, %1, off sc0 sc1"
                     : "=v"(v[i]) : "v"(base + i * 256));
    asm volatile("s_waitcnt vmcnt(0)" ::: "memory");
    __builtin_amdgcn_sched_barrier(0);
    float s = 0.f;
#pragma unroll
    for (int i = 0; i < 32; i++) s += v[i];
    return s;
}

// Wave-0 poll of 128 per-block flags (125 real + 3 preset-1 pad), coherent.
__device__ __forceinline__ void pollFlags(const int* fb, int lane) {
    for (;;) {
        int f0, f1;
        asm volatile("global_load_dword %0, %1, off sc0 sc1"
                     : "=v"(f0) : "v"(fb + lane));
        asm volatile("global_load_dword %0, %1, off sc0 sc1"
                     : "=v"(f1) : "v"(fb + 64 + lane));
        asm volatile("s_waitcnt vmcnt(0)" : "+v"(f0), "+v"(f1) :: "memory");
        __builtin_amdgcn_sched_barrier(0);
        if (__all((f0 == 1) && (f1 == 1))) return;
        __builtin_amdgcn_s_sleep(1);
    }
}

// K1: blocks 0..511: 16 rows each -> Fh/Fl + rnorm + g/wsum partials.
//     block 512: setup math + th2rr bf16 split + flag/pad init. (unchanged)
__global__ __launch_bounds__(256) void k_fr(
    const float* __restrict__ A, const float* __restrict__ b, const float* __restrict__ c,
    const float* __restrict__ th1r, const float* __restrict__ th1c,
    const float* __restrict__ th2rr, const float* __restrict__ th2rc,
    const float* __restrict__ th3rr, const float* __restrict__ th3rc, const float* __restrict__ th3cr,
    const float* __restrict__ th4rr, const float* __restrict__ th4rc, const float* __restrict__ th4cr,
    const int* __restrict__ zp,
    unsigned short* __restrict__ Fh, unsigned short* __restrict__ Fl,
    unsigned short* __restrict__ R2H, unsigned short* __restrict__ R2L,
    float* __restrict__ ws)
{
    int tid = threadIdx.x, lane = tid & 63, wid = tid >> 6;

    if (blockIdx.x == 512) {
        __shared__ float fcraw[64], fz[64], sh4a[64], sh4b[64];
        int p = lane;
        int z = zp[0];
        float cv = (p < 63) ? c[p] : 0.f;
        fcraw[p] = cv;
        float av = (p < 63) ? A[z * 63 + p] : b[z];
        float s2 = waveReduceSum(av * av);
        fz[p] = av * rsqrtf(s2);
        __syncthreads();

        float t1 = 0.f, t2 = 0.f, w0 = 0.f;
#pragma unroll 8
        for (int k = 0; k < 64; k++) {
            t1 += th1r[p * 64 + k] * fz[k];
            t2 += th1c[p * 64 + k] * fz[k];
            w0 += th2rc[p * 64 + k] * fcraw[k];
        }
        ws[WS_T1R + p] = t1;
        ws[WS_T1C + p] = t2;
        ws[WS_W + p] = t1 + w0;               // w for sweep 0

        sh4a[p] = th4rr[p];
        sh4b[p] = th4rc[p];
        __syncthreads();
        float a = 0.f, bb = 0.f, g = 0.f, d = 0.f;
#pragma unroll 8
        for (int k = 0; k < 64; k++) {
            float t4 = sh4a[k];
            a  += th3rr[p * 64 + k] * fmaxf(t4, 0.f);
            bb += th3rr[p * 64 + k] * fmaxf(-t4, 0.f);
            float t5 = sh4b[k];
            g  += th3rc[p * 64 + k] * fmaxf(t5, 0.f);
            d  += th3rc[p * 64 + k] * fmaxf(-t5, 0.f);
        }
        ws[WS_AL + p] = a; ws[WS_BE + p] = bb;
        ws[WS_GA + p] = g; ws[WS_DE + p] = d;
        __syncthreads();
        sh4a[p] = th4cr[p];
        __syncthreads();
        float e1 = 0.f, e2 = 0.f;
#pragma unroll 8
        for (int k = 0; k < 64; k++) {
            float t6 = sh4a[k];
            e1 += th3cr[p * 64 + k] * fmaxf(t6, 0.f);
            e2 += th3cr[p * 64 + k] * fmaxf(-t6, 0.f);
        }
        ws[WS_ECP + p] = e1; ws[WS_ECN + p] = e2;

        // flags: [5][128]; real blocks 0..124 start 0, pad 125..127 preset 1
        if (tid < 128) {
            int* fl = (int*)(ws + WS_FLAG);
#pragma unroll
            for (int t5 = 0; t5 < 5; t5++)
                fl[t5 * 128 + tid] = (tid >= NBLK) ? 1 : 0;
        }
        // zero CPART pad rows (blk 125..127) for all 5 sweeps (+0.0f bit-exact)
        if (tid < 192) {
#pragma unroll
            for (int t5 = 0; t5 < 5; t5++)
                ws[WS_CPART + t5 * 8192 + 8000 + tid] = 0.f;
        }

#pragma unroll
        for (int i = 0; i < 16; i++) {
            int idx = tid * 16 + i;
            float f = th2rr[idx];
            unsigned short h = f2bf(f);
            R2H[idx] = h;
            R2L[idx] = f2bf(f - bf2f(h));
        }
        return;
    }

    __shared__ float gsh[64];
    __shared__ float wsh2[2];
    if (tid < 64) gsh[tid] = 0.f;
    if (tid < 2) wsh2[tid] = 0.f;
    __syncthreads();

    float cv = (lane < 63) ? c[lane] : 0.f;
    float cn2 = waveReduceSum(cv * cv);
    float fcnl = cv * rsqrtf(cn2);

    int r0 = blockIdx.x * 16 + wid * 4;
    float gl = 0.f, lp = 0.f, ln = 0.f;
#pragma unroll
    for (int i = 0; i < 4; i++) {
        int r = r0 + i;
        if (r < 8000) {
            float val = (lane < 63) ? A[r * 63 + lane] : b[r];
            float s2 = waveReduceSum(val * val);
            float f = val * rsqrtf(s2);
            unsigned short h = f2bf(f);
            Fh[r * 64 + lane] = h;
            Fl[r * 64 + lane] = f2bf(f - bf2f(h));
            gl += f;
            float w = waveReduceSum(f * fcnl);
            if (lane == 0) {
                ws[WS_RNORM + r] = sqrtf(s2);
                lp += fmaxf(w, 0.f); ln += fmaxf(-w, 0.f);
            }
        } else {
            Fh[r * 64 + lane] = 0;
            Fl[r * 64 + lane] = 0;
        }
    }
    atomicAdd(&gsh[lane], gl);
    if (lane == 0) { atomicAdd(&wsh2[0], lp); atomicAdd(&wsh2[1], ln); }
    __syncthreads();
    if (tid < 64) ws[WS_GPART + blockIdx.x * 64 + tid] = gsh[tid];
    if (tid == 64) ws[WS_WPART + blockIdx.x * 2 + 0] = wsh2[0];
    if (tid == 65) ws[WS_WPART + blockIdx.x * 2 + 1] = wsh2[1];
}

// K2: SYMMETRIC bf16 MFMA gram. Grid (32,32); only tx<=ty blocks compute
// (528 of 1024): tile (tx,ty) = W[v in tx*256.., u in ty*256..].
// Row relu-sums (over u) -> SPART[ty][v]; col relu-sums (over v, symmetry)
// -> SPART[tx][u] (off-diagonal only). Every slot written exactly once, so
// the 32-slot reduction downstream is unchanged. Block (1,0) (otherwise
// idle) reduces GPART->gS and WPART->WSUM once for the whole device.
__global__ __launch_bounds__(256) void k_gram(
    const unsigned short* __restrict__ Fh, float* __restrict__ ws)
{
    __shared__ float red[256];
    __shared__ float colw[4][16][16];
    int tid = threadIdx.x, lane = tid & 63, wid = tid >> 6;
    int m = lane & 15, quad = lane >> 4;
    int tx = blockIdx.x, ty = blockIdx.y;

    if (tx > ty) {
        if (tx == 1 && ty == 0) {
            float gv = 0.f;
#pragma unroll 32
            for (int bb = 0; bb < 128; bb++)
                gv += ws[WS_GPART + (wid * 128 + bb) * 64 + lane];
            red[tid] = gv;
            if (wid == 1) {
                float wp = 0.f;
#pragma unroll
                for (int k = 0; k < 8; k++) wp += ws[WS_WPART + (lane + 64 * k) * 2];
                wp = waveReduceSum(wp);
                if (lane == 0) ws[WS_WSUM] = wp;
            } else if (wid == 2) {
                float wn = 0.f;
#pragma unroll
                for (int k = 0; k < 8; k++) wn += ws[WS_WPART + (lane + 64 * k) * 2 + 1];
                wn = waveReduceSum(wn);
                if (lane == 0) ws[WS_WSUM + 1] = wn;
            }
            __syncthreads();
            if (tid < 64)
                ws[WS_GS + tid] = red[tid] + red[64 + tid] + red[128 + tid] + red[192 + tid];
        }
        return;
    }

    int vbase = tx * 256 + wid * 64;
    int ubase = ty * 256;

    short8 AH[8];
#pragma unroll
    for (int pt = 0; pt < 4; pt++)
#pragma unroll
        for (int q = 0; q < 2; q++)
            AH[pt * 2 + q] = *(const short8*)(Fh + (vbase + pt * 16 + m) * 64 + q * 32 + quad * 8);

    float srr[16];
#pragma unroll
    for (int i = 0; i < 16; i++) srr[i] = 0.f;

    const int boff = m * 64 + quad * 8;
    const int ub = ubase * 64;
    short8 B0[2], B1[2];
#pragma unroll
    for (int q = 0; q < 2; q++)
        B0[q] = *(const short8*)(Fh + ub + boff + q * 32);

#pragma unroll 1
    for (int k2 = 0; k2 < 8; k2++) {
#pragma unroll
        for (int q = 0; q < 2; q++)
            B1[q] = *(const short8*)(Fh + ub + (2 * k2 + 1) * 1024 + boff + q * 32);
        {
            float cs = 0.f;
#pragma unroll
            for (int pt = 0; pt < 4; pt++) {
                f32x4 a = {0.f, 0.f, 0.f, 0.f};
                a = __builtin_amdgcn_mfma_f32_16x16x32_bf16(AH[pt * 2 + 0], B0[0], a, 0, 0, 0);
                a = __builtin_amdgcn_mfma_f32_16x16x32_bf16(AH[pt * 2 + 1], B0[1], a, 0, 0, 0);
#pragma unroll
                for (int r = 0; r < 4; r++) {
                    float rr = fmaxf(a[r], 0.f);
                    srr[pt * 4 + r] += rr; cs += rr;
                }
            }
            cs += __shfl_xor(cs, 16, 64);
            cs += __shfl_xor(cs, 32, 64);
            if (quad == 0) colw[wid][2 * k2][m] = cs;
        }
        if (k2 < 7)
#pragma unroll
            for (int q = 0; q < 2; q++)
                B0[q] = *(const short8*)(Fh + ub + (2 * k2 + 2) * 1024 + boff + q * 32);
        {
            float cs = 0.f;
#pragma unroll
            for (int pt = 0; pt < 4; pt++) {
                f32x4 a = {0.f, 0.f, 0.f, 0.f};
                a = __builtin_amdgcn_mfma_f32_16x16x32_bf16(AH[pt * 2 + 0], B1[0], a, 0, 0, 0);
                a = __builtin_amdgcn_mfma_f32_16x16x32_bf16(AH[pt * 2 + 1], B1[1], a, 0, 0, 0);
#pragma unroll
                for (int r = 0; r < 4; r++) {
                    float rr = fmaxf(a[r], 0.f);
                    srr[pt * 4 + r] += rr; cs += rr;
                }
            }
            cs += __shfl_xor(cs, 16, 64);
            cs += __shfl_xor(cs, 32, 64);
            if (quad == 0) colw[wid][2 * k2 + 1][m] = cs;
        }
    }
    __syncthreads();
    // row partials: v in tx tile, slot ty
#pragma unroll
    for (int pt = 0; pt < 4; pt++)
#pragma unroll
        for (int r = 0; r < 4; r++) {
            float s = srr[pt * 4 + r];
            s += __shfl_xor(s, 1, 64); s += __shfl_xor(s, 2, 64);
            s += __shfl_xor(s, 4, 64); s += __shfl_xor(s, 8, 64);
            if (m == 0)
                ws[WS_SPART + ty * 8192 + vbase + pt * 16 + quad * 4 + r] = s;
        }
    // col partials (symmetry): u in ty tile, slot tx — off-diagonal only
    if (tx < ty) {
        float csum = colw[0][tid >> 4][tid & 15] + colw[1][tid >> 4][tid & 15]
                   + colw[2][tid >> 4][tid & 15] + colw[3][tid >> 4][tid & 15];
        ws[WS_SPART + tx * 8192 + ubase + tid] = csum;
    }
}

// K3: fused mu0 + 4 sweeps + head, ONE cooperative kernel, 125x256.
// Sweep matvec operands (th2cr/th2rc rows, t1r/t1c/ecp/ecn/wsum) cached in
// registers; gS/WSUM precomputed by k_gram's reducer block.
__global__ __launch_bounds__(256) void k_mu_fused(
    const float* __restrict__ c,
    const float* __restrict__ th2cr, const float* __restrict__ th2rc,
    const float* __restrict__ th6r, const float* __restrict__ th6c,
    const float* __restrict__ th7, const float* __restrict__ W8,
    const float* __restrict__ b8, const int* __restrict__ zp,
    float* __restrict__ ws,
    const unsigned short* __restrict__ Fh, const unsigned short* __restrict__ Fl,
    const unsigned short* __restrict__ R2H, const unsigned short* __restrict__ R2L,
    float* __restrict__ out)
{
    __shared__ float XF[64][68];
    __shared__ unsigned short UHT[64][72], ULT[64][72];   // mu state, padded
    __shared__ float red[256], colp[256];
    __shared__ __align__(16) float wS[64], alS[64], beS[64], gaS[64], deS[64];
    __shared__ float fcnS[64], gS[64], sprow[64];
    __shared__ __align__(16) float e4sh[256];
    __shared__ float Ssh[64], ysh[64], feat[128], muzS[64];

    int tid = threadIdx.x, lane = tid & 63, wid = tid >> 6;
    int m = lane & 15, quad = lane >> 4;
    int v0 = blockIdx.x * 64;
    int cw = wid * 16 + m;
    int v = v0 + cw;
    int z = zp[0];
    int* flags = (int*)(ws + WS_FLAG);

    // persistent A-fragments (th2rr hi/lo) — loaded ONCE for all 5 sweeps
    short8 RH[8], RL[8];
#pragma unroll
    for (int pt = 0; pt < 4; pt++)
#pragma unroll
        for (int q = 0; q < 2; q++) {
            int off = (pt * 16 + m) * 64 + q * 32 + quad * 8;
            RH[pt * 2 + q] = *(const short8*)(R2H + off);
            RL[pt * 2 + q] = *(const short8*)(R2L + off);
        }

    // per-thread cached matvec operands (p = wid*16 + m fixed per thread)
    int prow = wid * 16 + m;
    float4 Tcr[4], Trc[4];
#pragma unroll
    for (int kk = 0; kk < 4; kk++) {
        Tcr[kk] = ((const float4*)(th2cr + prow * 64 + quad * 16))[kk];
        Trc[kk] = ((const float4*)(th2rc + prow * 64 + quad * 16))[kk];
    }
    float t1c_r = ws[WS_T1C + prow], t1r_r = ws[WS_T1R + prow];
    float ecp_r = ws[WS_ECP + prow], ecn_r = ws[WS_ECN + prow];
    float wsp = ws[WS_WSUM], wsn = ws[WS_WSUM + 1];

    // ---------------- phase 0: e4 + mu0 prep ----------------
    if (wid == 0) {
        float cv = (lane < 63) ? c[lane] : 0.f;
        float cn2 = waveReduceSum(cv * cv);
        fcnS[lane] = cv * rsqrtf(cn2);
        wS[lane] = ws[WS_W + lane];
    } else if (wid == 1) {
        alS[lane] = ws[WS_AL + lane]; beS[lane] = ws[WS_BE + lane];
    } else if (wid == 2) {
        gaS[lane] = ws[WS_GA + lane]; deS[lane] = ws[WS_DE + lane];
    } else {
        gS[lane] = ws[WS_GS + lane];          // precomputed by k_gram reducer
    }
    float sv = 0.f;
#pragma unroll
    for (int y = wid * 8; y < wid * 8 + 8; y++) sv += ws[WS_SPART + y * 8192 + v0 + lane];
    red[tid] = sv;
    __syncthreads();
    if (tid < 64) sprow[tid] = red[tid] + red[64 + tid] + red[128 + tid] + red[192 + tid];
    __syncthreads();

    for (int i2 = 0; i2 < 16; i2++) {
        int i = wid * 16 + i2;
        int vr = v0 + i;
        float fr = bf2f(Fh[vr * 64 + lane]) + bf2f(Fl[vr * 64 + lane]);
        float dw = waveReduceSum(fr * fcnS[lane]);
        float dg = waveReduceSum(fr * gS[lane]);
        if (lane == 0) {
            float spv = sprow[i];
            float4 ee;
            ee.x = spv - 1.0f;         // remove diagonal relu(1)
            ee.y = spv - dg;           // relu(-x) = relu(x) - x
            ee.z = fmaxf(dw, 0.f);
            ee.w = fmaxf(-dw, 0.f);
            *(float4*)(&e4sh[i * 4]) = ee;
        }
        XF[i][lane] = fr * ws[WS_RNORM + vr];   // mu0 row (fp32)
    }
    __syncthreads();

    short8 BH[2], BL[2];
#pragma unroll
    for (int q = 0; q < 2; q++) {
        float4 f0 = *(const float4*)(&XF[cw][q * 32 + quad * 8]);
        float4 f1 = *(const float4*)(&XF[cw][q * 32 + quad * 8 + 4]);
        float xv[8] = {f0.x, f0.y, f0.z, f0.w, f1.x, f1.y, f1.z, f1.w};
        short8 H, L;
#pragma unroll
        for (int j = 0; j < 8; j++) {
            unsigned short h = f2bf(xv[j]);
            H[j] = (short)h;
            L[j] = (short)f2bf(xv[j] - bf2f(h));
        }
        BH[q] = H; BL[q] = L;
    }
    float4 e = *(const float4*)(&e4sh[cw * 4]);   // persistent for all sweeps

    // ---------------- sweeps 0..4 ----------------
    for (int t = 0; t < 5; t++) {
        if (t > 0) {
            // mu(t-1) fragments from LDS (written last sweep, synced)
#pragma unroll
            for (int q = 0; q < 2; q++) {
                BH[q] = *(const short8*)(&UHT[cw][q * 32 + quad * 8]);
                BL[q] = *(const short8*)(&ULT[cw][q * 32 + quad * 8]);
            }
        }
        // ---- MFMA first: no cross-block dependency; hides flag latency
        f32x4 acc[4];
#pragma unroll
        for (int pt = 0; pt < 4; pt++) {
            f32x4 a = {0.f, 0.f, 0.f, 0.f};
#pragma unroll
            for (int q = 0; q < 2; q++) {
                a = __builtin_amdgcn_mfma_f32_16x16x32_bf16(RH[pt*2+q], BH[q], a, 0, 0, 0);
                a = __builtin_amdgcn_mfma_f32_16x16x32_bf16(RH[pt*2+q], BL[q], a, 0, 0, 0);
                a = __builtin_amdgcn_mfma_f32_16x16x32_bf16(RL[pt*2+q], BH[q], a, 0, 0, 0);
            }
            acc[pt] = a;
        }

        if (t > 0) {
            // ---- wait for CPART(t-1) producers (flags likely already set)
            if (wid == 0) pollFlags(flags + (t - 1) * 128, lane);
            __syncthreads();
            // Ssh = reduce CPART(t-1): batched coherent loads, fixed order
            red[tid] = sum32_coherent(ws + WS_CPART + (t - 1) * 8192 + wid * 64 + lane);
            __syncthreads();
            if (tid < 64) Ssh[tid] = red[tid] + red[64 + tid] + red[128 + tid] + red[192 + tid];
            __syncthreads();
            {
                float acc2 = 0.f;
#pragma unroll
                for (int kk = 0; kk < 4; kk++) {
                    float4 r4 = Tcr[kk];
                    acc2 += r4.x * Ssh[quad * 16 + 4 * kk]     + r4.y * Ssh[quad * 16 + 4 * kk + 1]
                          + r4.z * Ssh[quad * 16 + 4 * kk + 2] + r4.w * Ssh[quad * 16 + 4 * kk + 3];
                }
                acc2 += __shfl_xor(acc2, 16, 64);
                acc2 += __shfl_xor(acc2, 32, 64);
                if (quad == 0)
                    ysh[prow] = fmaxf(acc2 + t1c_r + wsp * ecp_r + wsn * ecn_r, 0.f);
            }
            __syncthreads();
            {
                float acc2 = 0.f;
#pragma unroll
                for (int kk = 0; kk < 4; kk++) {
                    float4 r4 = Trc[kk];
                    acc2 += r4.x * ysh[quad * 16 + 4 * kk]     + r4.y * ysh[quad * 16 + 4 * kk + 1]
                          + r4.z * ysh[quad * 16 + 4 * kk + 2] + r4.w * ysh[quad * 16 + 4 * kk + 3];
                }
                acc2 += __shfl_xor(acc2, 16, 64);
                acc2 += __shfl_xor(acc2, 32, 64);
                if (quad == 0) wS[prow] = acc2 + t1r_r;
            }
            __syncthreads();   // wS ready
        }

        // ---- epilogue
#pragma unroll
        for (int pt = 0; pt < 4; pt++) {
            f32x4 a = acc[pt];
            int pbase = pt * 16 + quad * 4;
            float4 w4 = *(const float4*)(wS + pbase);
            float4 a4 = *(const float4*)(alS + pbase);
            float4 b4 = *(const float4*)(beS + pbase);
            float4 g4 = *(const float4*)(gaS + pbase);
            float4 d4 = *(const float4*)(deS + pbase);
            float u0 = fmaxf(a[0] + w4.x + a4.x*e.x + b4.x*e.y + g4.x*e.z + d4.x*e.w, 0.f);
            float u1 = fmaxf(a[1] + w4.y + a4.y*e.x + b4.y*e.y + g4.y*e.z + d4.y*e.w, 0.f);
            float u2 = fmaxf(a[2] + w4.z + a4.z*e.x + b4.z*e.y + g4.z*e.z + d4.z*e.w, 0.f);
            float u3 = fmaxf(a[3] + w4.w + a4.w*e.x + b4.w*e.y + g4.w*e.z + d4.w*e.w, 0.f);
            if (t < 4) {
                ushort4 h4, l4;
                h4.x = f2bf(u0); l4.x = f2bf(u0 - bf2f(h4.x));
                h4.y = f2bf(u1); l4.y = f2bf(u1 - bf2f(h4.y));
                h4.z = f2bf(u2); l4.z = f2bf(u2 - bf2f(h4.z));
                h4.w = f2bf(u3); l4.w = f2bf(u3 - bf2f(h4.w));
                *(ushort4*)(&UHT[cw][pbase]) = h4;
                *(ushort4*)(&ULT[cw][pbase]) = l4;
            } else if (v == z) {
                __hip_atomic_store(&ws[WS_MUZ + pbase + 0], u0, __ATOMIC_RELAXED, __HIP_MEMORY_SCOPE_AGENT);
                __hip_atomic_store(&ws[WS_MUZ + pbase + 1], u1, __ATOMIC_RELAXED, __HIP_MEMORY_SCOPE_AGENT);
                __hip_atomic_store(&ws[WS_MUZ + pbase + 2], u2, __ATOMIC_RELAXED, __HIP_MEMORY_SCOPE_AGENT);
                __hip_atomic_store(&ws[WS_MUZ + pbase + 3], u3, __ATOMIC_RELAXED, __HIP_MEMORY_SCOPE_AGENT);
            }
            float c0 = u0, c1 = u1, c2 = u2, c3 = u3;
#pragma unroll
            for (int mm = 1; mm < 16; mm <<= 1) {
                c0 += __shfl_xor(c0, mm, 64);
                c1 += __shfl_xor(c1, mm, 64);
                c2 += __shfl_xor(c2, mm, 64);
                c3 += __shfl_xor(c3, mm, 64);
            }
            if (m == 0) {
                colp[wid * 64 + pbase + 0] = c0;
                colp[wid * 64 + pbase + 1] = c1;
                colp[wid * 64 + pbase + 2] = c2;
                colp[wid * 64 + pbase + 3] = c3;
            }
        }
        __syncthreads();
        if (tid < 64)
            __hip_atomic_store(&ws[WS_CPART + t * 8192 + blockIdx.x * 64 + tid],
                               colp[tid] + colp[64 + tid] + colp[128 + tid] + colp[192 + tid],
                               __ATOMIC_RELAXED, __HIP_MEMORY_SCOPE_AGENT);
        // per-wave vmcnt(0) drain before s_barrier ⇒ CPART at coherence point
        __syncthreads();
        if (tid == 0) {
            asm volatile("s_waitcnt vmcnt(0)" ::: "memory");
            __hip_atomic_store(&flags[t * 128 + (int)blockIdx.x], 1,
                               __ATOMIC_RELAXED, __HIP_MEMORY_SCOPE_AGENT);
        }
    }

    // ---------------- head (block 0 only) ----------------
    if (blockIdx.x != 0) return;

    if (wid == 0) pollFlags(flags + 4 * 128, lane);
    __syncthreads();

    red[tid] = sum32_coherent(ws + WS_CPART + 4 * 8192 + wid * 64 + lane);
    if (tid < 64) {       // stage mu[z] with ONE coherent load per lane
        float mz;
        asm volatile("global_load_dword %0, %1, off sc0 sc1"
                     : "=v"(mz) : "v"(ws + WS_MUZ + tid));
        asm volatile("s_waitcnt vmcnt(0)" : "+v"(mz) :: "memory");
        __builtin_amdgcn_sched_barrier(0);
        muzS[tid] = mz;
    }
    __syncthreads();
    if (tid < 64) Ssh[tid] = red[tid] + red[64 + tid] + red[128 + tid] + red[192 + tid];
    __syncthreads();
    int p = tid;
    if (p < 64) {
        float acc2 = ws[WS_T1C + p] + ws[WS_WSUM] * ws[WS_ECP + p]
                   + ws[WS_WSUM + 1] * ws[WS_ECN + p];
#pragma unroll 8
        for (int k = 0; k < 64; k++) acc2 += th2cr[p * 64 + k] * Ssh[k];
        ysh[p] = fmaxf(acc2, 0.f);
    }
    __syncthreads();
    if (p < 64) {
        float t6 = 0.f, t7 = 0.f;
#pragma unroll 8
        for (int k = 0; k < 64; k++) {
            t6 += th6r[p * 64 + k] * Ssh[k] + th6c[p * 64 + k] * ysh[k];
            t7 += th7[p * 64 + k] * muzS[k];
        }
        feat[p] = 1.f / (1.f + expf(-t6));
        feat[64 + p] = 1.f / (1.f + expf(-t7));
    }
    __syncthreads();
    if (p < 2) {
        float o = b8[p];
        for (int i = 0; i < 128; i++) o += W8[p * 128 + i] * feat[i];
        out[p] = o;
    }
}

extern "C" void kernel_launch(void* const* d_in, const int* in_sizes, int n_in,
                              void* d_out, int out_size, void* d_ws, size_t ws_size,
                              hipStream_t stream) {
    (void)in_sizes; (void)n_in; (void)out_size; (void)ws_size;
    const float* A     = (const float*)d_in[0];
    const float* b     = (const float*)d_in[1];
    const float* c     = (const float*)d_in[2];
    const float* th1r  = (const float*)d_in[3];
    const float* th1c  = (const float*)d_in[4];
    const float* th2rr = (const float*)d_in[5];
    const float* th2rc = (const float*)d_in[6];
    const float* th2cr = (const float*)d_in[7];
    const float* th3rr = (const float*)d_in[8];
    const float* th3rc = (const float*)d_in[9];
    const float* th3cr = (const float*)d_in[10];
    const float* th4rr = (const float*)d_in[11];
    const float* th4rc = (const float*)d_in[12];
    const float* th4cr = (const float*)d_in[13];
    const float* th6r  = (const float*)d_in[14];
    const float* th6c  = (const float*)d_in[15];
    const float* th7   = (const float*)d_in[16];
    const float* W8    = (const float*)d_in[17];
    const float* b8    = (const float*)d_in[18];
    const int*   zp    = (const int*)d_in[19];
    float* ws  = (float*)d_ws;
    float* out = (float*)d_out;
    unsigned short* Fh  = (unsigned short*)(ws + WS_FH);
    unsigned short* Fl  = (unsigned short*)(ws + WS_FL);
    unsigned short* R2H = (unsigned short*)(ws + WS_R2H);
    unsigned short* R2L = (unsigned short*)(ws + WS_R2L);

    k_fr<<<513, 256, 0, stream>>>(A, b, c, th1r, th1c, th2rr, th2rc, th3rr, th3rc,
                                  th3cr, th4rr, th4rc, th4cr, zp, Fh, Fl, R2H, R2L, ws);
    k_gram<<<dim3(32, 32), 256, 0, stream>>>(Fh, ws);
    {
        const unsigned short* Fhc = Fh;
        const unsigned short* Flc = Fl;
        const unsigned short* R2Hc = R2H;
        const unsigned short* R2Lc = R2L;
        void* kargs[] = {
            (void*)&c, (void*)&th2cr, (void*)&th2rc, (void*)&th6r, (void*)&th6c,
            (void*)&th7, (void*)&W8, (void*)&b8, (void*)&zp, (void*)&ws,
            (void*)&Fhc, (void*)&Flc, (void*)&R2Hc, (void*)&R2Lc, (void*)&out };
        hipLaunchCooperativeKernel((const void*)k_mu_fused, dim3(NBLK), dim3(256),
                                   kargs, 0, stream);
    }
}